// Round 14
// baseline (114.415 us; speedup 1.0000x reference)
//
#include <hip/hip_runtime.h>
#include <hip/hip_bf16.h>

// out = softmax((X Wq + bq)(X Wk + bk)^T / 8) (X Wv + bv) Wo + bo
// All prune/straight-through ops in the reference are value-wise identity.
//
//   k_prep: fused {hs->bf16 A | W^T bf16 x4 | kh/vt pad zero}   (round-6 proven)
//   k_gemm: 128x128 tile, 512 thr / 8 waves, dbuf gload_lds vmcnt(4),
//           XCD-chunked swizzle, LDS-staged coalesced epilogue  (round-6 proven)
//   k_attn: BARRIER-FREE flash attention with PRIVATE per-wave K/V staging:
//           each wave = (head, 32 q-rows), own double-buffered K/V LDS tiles
//           filled by its own global_load_lds (own-wave vmcnt = completion,
//           no s_barrier anywhere), depth-1 prefetch vmcnt(16). 2 waves/block,
//           72KB LDS -> 2 blocks/CU -> cross-block slip. Round-6 frag math.

#define B_ 8
#define S_ 577
#define H_ 768
#define NH_ 12
#define HD_ 64
#define M_ (B_*S_)     /* 4616 */
#define MPAD 4736
#define BH_ (B_*NH_)   /* 96 */
#define SKPAD 640      /* padded key count */
#define LTS 136        /* padded LDS row stride (shorts) for epilogue tile */

typedef __attribute__((ext_vector_type(8))) short short8;
typedef __attribute__((ext_vector_type(4))) short s16x4;
typedef __attribute__((ext_vector_type(4))) float f32x4;

__device__ inline unsigned short f2bf(float f){
    unsigned int u = __float_as_uint(f);
    u = u + 0x7fffu + ((u>>16)&1u);     // round-to-nearest-even
    return (unsigned short)(u>>16);
}

__device__ inline void gload_lds16(const short* g, short* l){
    __builtin_amdgcn_global_load_lds((const __attribute__((address_space(1))) void*)g,
                                     (__attribute__((address_space(3))) void*)l, 16, 0, 0);
}

// fused prep: blocks [0,1776) cvt | [1776,2352) wt | [2352,2733) pad
__global__ __launch_bounds__(256) void k_prep(
    const float* __restrict__ hs, short* __restrict__ abf,
    const float* __restrict__ Wq, const float* __restrict__ Wk,
    const float* __restrict__ Wv, const float* __restrict__ Wo,
    short* __restrict__ Tq, short* __restrict__ Tk,
    short* __restrict__ Tv, short* __restrict__ To,
    short* __restrict__ kh, short* __restrict__ vt)
{
    const int bid = blockIdx.x, t = threadIdx.x;
    if(bid < 1776){
        int i = bid*256 + t;
        if(bid >= 1731){ *(short8*)(abf + (size_t)i*8) = (short8){}; return; }
        const float4* p = (const float4*)(hs + (size_t)i*8);
        float4 a = p[0], b = p[1];
        short8 v;
        v[0]=(short)f2bf(a.x); v[1]=(short)f2bf(a.y); v[2]=(short)f2bf(a.z); v[3]=(short)f2bf(a.w);
        v[4]=(short)f2bf(b.x); v[5]=(short)f2bf(b.y); v[6]=(short)f2bf(b.z); v[7]=(short)f2bf(b.w);
        *(short8*)(abf + (size_t)i*8) = v;
    } else if(bid < 2352){
        int zidx = bid - 1776;
        int z = zidx & 3, rem = zidx >> 2;
        int kx = rem % 12, ny = rem / 12;
        const float* W = z==0?Wq: z==1?Wk: z==2?Wv:Wo;
        short*       T = z==0?Tq: z==1?Tk: z==2?Tv:To;
        __shared__ float lds[64][65];
        int k0 = kx*64, n0 = ny*64;
        for(int i=0;i<4;i++){
            int row = i*16 + (t>>4);
            int col = (t&15)*4;
            float4 v = *(const float4*)&W[(k0+row)*768 + n0 + col];
            lds[row][col]=v.x; lds[row][col+1]=v.y; lds[row][col+2]=v.z; lds[row][col+3]=v.w;
        }
        __syncthreads();
        for(int i=0;i<4;i++){
            int n = i*16 + (t>>4);
            int k4 = (t&15)*4;
            for(int j=0;j<4;j++)
                T[(n0+n)*768 + k0 + k4 + j] = (short)f2bf(lds[k4+j][n]);
        }
    } else {
        int tid = (bid-2352)*256 + t;
        short8 z = {};
        if(tid < 48384){
            int row_id = tid>>3, ch = tid&7;
            int bh = row_id/63, r = row_id - bh*63;
            *(short8*)&kh[((size_t)bh*SKPAD + 577 + r)*64 + ch*8] = z;
        } else if(tid < 97536){
            int j = tid - 48384;
            int row_id = j>>3, ch = j&7;
            int bh = row_id>>6, d = row_id&63;
            *(short8*)&vt[((size_t)bh*64 + d)*SKPAD + 576 + ch*8] = z;
        }
    }
}

// 128x128 tile GEMM, 512 threads / 8 waves, double-buffered counted-vmcnt K-loop,
// XCD-chunked swizzle. mode 0: QKV fused; mode 3: ctx@Wo+bo -> fp32  (round-6)
__global__ __launch_bounds__(512) void k_gemm(
    const short* __restrict__ A, const short* __restrict__ T,
    const float* __restrict__ b0, const float* __restrict__ b1, const float* __restrict__ b2,
    short* __restrict__ oq, short* __restrict__ ok, short* __restrict__ ovt,
    float* __restrict__ of, int mode, int NT)
{
    __shared__ short sh[32768];            // 64KB: dbuf K-loop; epilogue reuses [0,17408)
    const int t = threadIdx.x;

    const int nwg = gridDim.x;
    const int q8 = nwg>>3, r8 = nwg&7;
    const int xcd = blockIdx.x&7, cidx = blockIdx.x>>3;
    const int wg = (xcd<r8 ? xcd*(q8+1) : r8*(q8+1) + (xcd-r8)*q8) + cidx;
    const int mt = wg/NT, ntile = wg - mt*NT;
    const int m0 = mt*128, n0 = ntile*128;

    const int seg = (mode==3)? 0 : n0/768;
    const float* bias = (mode==3)? b0 : (seg==0?b0: seg==1?b1:b2);
    const int nlb = (mode==3)? n0 : n0 - seg*768;

    const int w = t>>6, lane = t&63, g = lane>>4, c = lane&15;
    const int wm = w>>1, wn = w&1;

    const int lrow = lane>>3;
    const int lcol = ((lane&7) ^ lrow) * 8;
    const short* pa = A + (size_t)(m0 + w*8 + lrow)*768 + lcol;
    const short* pb = T + (size_t)(n0 + w*8 + lrow)*768 + lcol;

    f32x4 acc[2][4] = {};

    #pragma unroll
    for(int i=0;i<2;i++){
        gload_lds16(pa + (size_t)(i*64)*768, &sh[(i*64 + w*8)*64]);
        gload_lds16(pb + (size_t)(i*64)*768, &sh[8192 + (i*64 + w*8)*64]);
    }
    int bb = 0;
    for(int kk=0; kk<12; kk++){
        if(kk<11){
            short* dstA = &sh[(bb^1)*16384];
            short* dstB = dstA + 8192;
            #pragma unroll
            for(int i=0;i<2;i++){
                gload_lds16(pa + (size_t)(i*64)*768 + (kk+1)*64, &dstA[(i*64 + w*8)*64]);
                gload_lds16(pb + (size_t)(i*64)*768 + (kk+1)*64, &dstB[(i*64 + w*8)*64]);
            }
            asm volatile("s_waitcnt vmcnt(4)" ::: "memory");
        } else {
            asm volatile("s_waitcnt vmcnt(0)" ::: "memory");
        }
        __builtin_amdgcn_s_barrier();
        asm volatile("" ::: "memory");

        const short* LA = &sh[bb*16384];
        const short* LB = LA + 8192;
        short8 af[2][2], bfv[4][2];
        #pragma unroll
        for(int mi=0; mi<2; mi++){
            int row = wm*32 + mi*16 + c;
            int rx = (row&7)<<3;
            af[mi][0] = *(const short8*)&LA[row*64 + ((g*8) ^ rx)];
            af[mi][1] = *(const short8*)&LA[row*64 + ((32 + g*8) ^ rx)];
        }
        #pragma unroll
        for(int ni=0; ni<4; ni++){
            int row = wn*64 + ni*16 + c;
            int rx = (row&7)<<3;
            bfv[ni][0] = *(const short8*)&LB[row*64 + ((g*8) ^ rx)];
            bfv[ni][1] = *(const short8*)&LB[row*64 + ((32 + g*8) ^ rx)];
        }
        __builtin_amdgcn_s_setprio(1);
        #pragma unroll
        for(int mi=0; mi<2; mi++)
            #pragma unroll
            for(int ni=0; ni<4; ni++){
                acc[mi][ni] = __builtin_amdgcn_mfma_f32_16x16x32_bf16(af[mi][0], bfv[ni][0], acc[mi][ni], 0,0,0);
                acc[mi][ni] = __builtin_amdgcn_mfma_f32_16x16x32_bf16(af[mi][1], bfv[ni][1], acc[mi][ni], 0,0,0);
            }
        __builtin_amdgcn_s_setprio(0);
        asm volatile("s_waitcnt lgkmcnt(0)" ::: "memory");
        __builtin_amdgcn_s_barrier();
        asm volatile("" ::: "memory");
        bb ^= 1;
    }

    if(mode==3){
        #pragma unroll
        for(int mi=0; mi<2; mi++) for(int ni=0; ni<4; ni++){
            #pragma unroll
            for(int r=0; r<4; r++){
                int m = m0 + wm*32 + mi*16 + g*4 + r;
                int n = n0 + wn*64 + ni*16 + c;
                if(m >= M_) continue;
                of[(size_t)m*768 + n] = acc[mi][ni][r] + bias[n];
            }
        }
        return;
    }

    if(seg==2){
        #pragma unroll
        for(int mi=0;mi<2;mi++)
            #pragma unroll
            for(int ni=0;ni<4;ni++){
                int nl_ = wn*64 + ni*16 + c;
                float bv = bias[nlb + nl_];
                s16x4 pk;
                #pragma unroll
                for(int r=0;r<4;r++) pk[r] = (short)f2bf(acc[mi][ni][r] + bv);
                int ml0 = wm*32 + mi*16 + g*4;
                *(s16x4*)&sh[nl_*LTS + ml0] = pk;       // transposed: [n][m]
            }
    } else {
        #pragma unroll
        for(int mi=0;mi<2;mi++)
            #pragma unroll
            for(int ni=0;ni<4;ni++){
                int nl_ = wn*64 + ni*16 + c;
                float bv = bias[nlb + nl_];
                #pragma unroll
                for(int r=0;r<4;r++){
                    int ml = wm*32 + mi*16 + g*4 + r;
                    sh[ml*LTS + nl_] = (short)f2bf(acc[mi][ni][r] + bv);
                }
            }
    }
    __syncthreads();

    #pragma unroll
    for(int i=0;i<4;i++){
        int idx = i*512 + t;
        int rp = idx>>4, ch = idx&15;
        short8 v8 = *(const short8*)&sh[rp*LTS + ch*8];
        if(seg==2){
            int nl = nlb + rp, hh = nl>>6, dd = nl&63;
            int mg = m0 + ch*8;
            if(mg < M_){
                int b0_ = mg/S_, s0 = mg - b0_*S_;
                if(s0+7 < S_ && mg+7 < M_){
                    *(short8*)&ovt[(((size_t)b0_*NH_+hh)*HD_+dd)*SKPAD + s0] = v8;
                } else {
                    for(int j=0;j<8;j++){
                        int m=mg+j;
                        if(m<M_){ int bj=m/S_, sj=m-bj*S_;
                            ovt[(((size_t)bj*NH_+hh)*HD_+dd)*SKPAD+sj]=v8[j]; }
                    }
                }
            }
        } else {
            int m = m0 + rp;
            if(m < M_){
                int b0_ = m/S_, s0 = m - b0_*S_;
                int nl = nlb + ch*8, hh = nl>>6, dd = nl&63;
                if(seg==1) *(short8*)&ok[(((size_t)b0_*NH_+hh)*SKPAD + s0)*HD_ + dd] = v8;
                else       *(short8*)&oq[(((size_t)b0_*NH_+hh)*S_   + s0)*HD_ + dd] = v8;
            }
        }
    }
}

// BARRIER-FREE flash attention with private per-wave K/V staging.
// Block = 2 waves; wave = (head, 32 q-rows). Each wave double-buffers its own
// 16KB K/V tile via its own global_load_lds (vmcnt(16) = depth-1 prefetch).
// No s_barrier anywhere. Round-6 fragment math / softmax / rowsum throughout.
__global__ __launch_bounds__(128) void k_attn(
    const short* __restrict__ qh, const short* __restrict__ kh, const short* __restrict__ vt,
    short* __restrict__ ctx)
{
    __shared__ short lKV[32768];    // [wave][buf][K 4096 | V 4096]
    __shared__ short lP[2*2048];
    const int t = threadIdx.x;
    const int w = t>>6, lane = t&63, g = lane>>4, c = lane&15;
    const int bh = blockIdx.x, b = bh/NH_, h = bh%NH_;
    const int q0 = blockIdx.y*64 + w*32;

    // Q staging into own lP region (own-wave write->read: compiler lgkmcnt)
    #pragma unroll
    for(int i=0;i<4;i++){
        int row = i*8 + (lane>>3);
        int e8 = (lane&7)*8;
        int s = q0 + row;
        short8 v = {};
        if(s < S_) v = *(const short8*)&qh[((size_t)bh*S_ + s)*HD_ + e8];
        *(short8*)&lP[w*2048 + row*64 + (e8 ^ ((row&7)<<3))] = v;
    }
    short8 qf[2][2];
    #pragma unroll
    for(int qi=0; qi<2; qi++)
        #pragma unroll
        for(int ks=0; ks<2; ks++)
            qf[qi][ks] = *(const short8*)&lP[w*2048 + (qi*16+c)*64 + ((ks*32+g*8) ^ ((c&7)<<3))];

    short8 ones;
    #pragma unroll
    for(int j=0;j<8;j++) ones[j] = (short)0x3F80;

    const int srow = lane>>3;
    const int sw8 = ((lane&7) ^ srow)*8;
    const short* pk0 = kh + ((size_t)bh*SKPAD + srow)*64 + sw8;
    const short* pv0 = vt + ((size_t)bh*64 + srow)*SKPAD + sw8;
    short* myKV = &lKV[w*16384];

    // stage full 64x64 K and V tiles for key-tile kt into own buffer (16 insts)
    #define STAGE(kt) { short* dK = &myKV[((kt)&1)*8192]; short* dV = dK + 4096; \
        _Pragma("unroll") for(int i_=0;i_<8;i_++){                               \
            gload_lds16(pk0 + ((size_t)(kt)*64 + i_*8)*64, &dK[i_*8*64]);        \
            gload_lds16(pv0 + (size_t)i_*8*SKPAD + (kt)*64, &dV[i_*8*64]); } }

    STAGE(0);

    float m_run[2][4], l_run[2][4];
    f32x4 O[2][4] = {};
    #pragma unroll
    for(int qi=0;qi<2;qi++)
        #pragma unroll
        for(int r=0;r<4;r++){ m_run[qi][r] = -3e38f; l_run[qi][r] = 0.f; }

    for(int kt=0; kt<10; kt++){
        if(kt<9){
            STAGE(kt+1);
            asm volatile("s_waitcnt vmcnt(16)" ::: "memory");   // tile kt complete
        } else {
            asm volatile("s_waitcnt vmcnt(0)" ::: "memory");
        }

        const short* LK = &myKV[(kt&1)*8192];
        const short* LV = LK + 4096;

        float sv[2][4][4];
        #pragma unroll
        for(int nt=0; nt<4; nt++){
            int row = nt*16 + c;
            int rx = (row&7)<<3;
            short8 kf[2];
            kf[0] = *(const short8*)&LK[row*64 + ((g*8) ^ rx)];
            kf[1] = *(const short8*)&LK[row*64 + ((32+g*8) ^ rx)];
            __builtin_amdgcn_s_setprio(1);
            #pragma unroll
            for(int qi=0; qi<2; qi++){
                f32x4 sa = {};
                sa = __builtin_amdgcn_mfma_f32_16x16x32_bf16(qf[qi][0], kf[0], sa, 0,0,0);
                sa = __builtin_amdgcn_mfma_f32_16x16x32_bf16(qf[qi][1], kf[1], sa, 0,0,0);
                #pragma unroll
                for(int r=0;r<4;r++) sv[qi][nt][r] = sa[r]*0.18033688011f;  // /8 * log2(e)
            }
            __builtin_amdgcn_s_setprio(0);
        }
        if(kt==9){
            #pragma unroll
            for(int nt=0; nt<4; nt++){
                int key = 576 + nt*16 + c;
                if(key >= S_){
                    #pragma unroll
                    for(int qi=0;qi<2;qi++)
                        #pragma unroll
                        for(int r=0;r<4;r++) sv[qi][nt][r] = -3e38f;
                }
            }
        }
        float fac[2][4];
        #pragma unroll
        for(int qi=0; qi<2; qi++)
            #pragma unroll
            for(int r=0;r<4;r++){
                float mx = fmaxf(fmaxf(sv[qi][0][r],sv[qi][1][r]),fmaxf(sv[qi][2][r],sv[qi][3][r]));
                for(int off=1; off<16; off<<=1) mx = fmaxf(mx, __shfl_xor(mx, off));
                float nm = fmaxf(m_run[qi][r], mx);
                fac[qi][r] = __builtin_amdgcn_exp2f(m_run[qi][r] - nm);
                m_run[qi][r] = nm;
            }
        #pragma unroll
        for(int qi=0; qi<2; qi++)
            #pragma unroll
            for(int nt=0; nt<4; nt++)
                #pragma unroll
                for(int r=0;r<4;r++){
                    float p = __builtin_amdgcn_exp2f(sv[qi][nt][r] - m_run[qi][r]);
                    int prow = g*4 + r;
                    lP[w*2048 + qi*1024 + prow*64 + ((nt*16 + c) ^ ((prow&7)<<3))] = (short)f2bf(p);
                }
        short8 pf[2][2];
        #pragma unroll
        for(int qi=0; qi<2; qi++)
            #pragma unroll
            for(int ks=0; ks<2; ks++)
                pf[qi][ks] = *(const short8*)&lP[w*2048 + qi*1024 + c*64 + ((ks*32+g*8) ^ ((c&7)<<3))];
        __builtin_amdgcn_s_setprio(1);
        #pragma unroll
        for(int qi=0; qi<2; qi++){
            f32x4 rs = {};
            rs = __builtin_amdgcn_mfma_f32_16x16x32_bf16(pf[qi][0], ones, rs, 0,0,0);
            rs = __builtin_amdgcn_mfma_f32_16x16x32_bf16(pf[qi][1], ones, rs, 0,0,0);
            #pragma unroll
            for(int r=0;r<4;r++) l_run[qi][r] = l_run[qi][r]*fac[qi][r] + rs[r];
        }
        __builtin_amdgcn_s_setprio(0);
        #pragma unroll
        for(int qi=0; qi<2; qi++)
            #pragma unroll
            for(int nt=0;nt<4;nt++)
                #pragma unroll
                for(int r=0;r<4;r++) O[qi][nt][r] *= fac[qi][r];

        __builtin_amdgcn_s_setprio(1);
        #pragma unroll
        for(int nt=0; nt<4; nt++){
            int vrow = nt*16 + c;
            int rx = (vrow&7)<<3;
            short8 vf[2];
            vf[0] = *(const short8*)&LV[vrow*64 + ((g*8) ^ rx)];
            vf[1] = *(const short8*)&LV[vrow*64 + ((32+g*8) ^ rx)];
            #pragma unroll
            for(int qi=0; qi<2; qi++){
                O[qi][nt] = __builtin_amdgcn_mfma_f32_16x16x32_bf16(pf[qi][0], vf[0], O[qi][nt], 0,0,0);
                O[qi][nt] = __builtin_amdgcn_mfma_f32_16x16x32_bf16(pf[qi][1], vf[1], O[qi][nt], 0,0,0);
            }
        }
        __builtin_amdgcn_s_setprio(0);
    }
    #undef STAGE

    #pragma unroll
    for(int qi=0; qi<2; qi++)
        #pragma unroll
        for(int nt=0; nt<4; nt++)
            #pragma unroll
            for(int r=0;r<4;r++){
                int s = q0 + qi*16 + g*4 + r;
                if(s < S_){
                    float val = O[qi][nt][r] / l_run[qi][r];
                    ctx[((size_t)b*S_ + s)*H_ + h*HD_ + nt*16 + c] = (short)f2bf(val);
                }
            }
}

extern "C" void kernel_launch(void* const* d_in, const int* in_sizes, int n_in,
                              void* d_out, int out_size, void* d_ws, size_t ws_size,
                              hipStream_t stream)
{
    const float* hs = (const float*)d_in[0];
    const float* Wq = (const float*)d_in[1];
    const float* bq = (const float*)d_in[2];
    const float* Wk = (const float*)d_in[3];
    const float* bk = (const float*)d_in[4];
    const float* Wv = (const float*)d_in[5];
    const float* bv = (const float*)d_in[6];
    const float* Wo = (const float*)d_in[7];
    const float* bo = (const float*)d_in[8];
    float* out = (float*)d_out;

    char* ws = (char*)d_ws;
    short* abf = (short*)(ws);
    short* ctx = abf;                               // reuse after QKV GEMM
    short* wqt = (short*)(ws + 7274496);
    short* wkt = (short*)(ws + 7274496 + 1179648);
    short* wvt = (short*)(ws + 7274496 + 2*1179648);
    short* wot = (short*)(ws + 7274496 + 3*1179648);
    short* qh  = (short*)(ws + 11993088);
    short* kh  = (short*)(ws + 19083264);
    short* vt  = (short*)(ws + 26947584);
    // total: 34,811,904 B

    k_prep<<<2733, 256, 0, stream>>>(hs, abf, Wq,Wk,Wv,Wo, wqt,wkt,wvt,wot, kh, vt);
    k_gemm<<<666, 512, 0, stream>>>(abf, wqt, bq,bk,bv, qh,kh,vt, nullptr, 0, 18);
    k_attn<<<dim3(96,10), 128, 0, stream>>>(qh, kh, vt, ctx);
    k_gemm<<<222, 512, 0, stream>>>(ctx, wot, bo,bo,bo, nullptr,nullptr,nullptr, out, 3, 6);
}

// Round 15
// 88.853 us; speedup vs baseline: 1.2877x; 1.2877x over previous
//
#include <hip/hip_runtime.h>
#include <hip/hip_bf16.h>

// out = softmax((X Wq + bq)(X Wk + bk)^T / 8) (X Wv + bv) Wo + bo
// All prune/straight-through ops in the reference are value-wise identity.
//
// Round-6 configuration (best measured: 91.9 us), reverted verbatim:
//   k_prep: fused {hs->bf16 A [4736][768] w/ zero pad | W^T bf16 x4 | kh/vt pad zero}
//   k_gemm: fused QKV GEMM (N=2304), 128x128 tile, 512 threads (8 waves,
//           per-wave 32x64), double-buffered gload_lds with counted vmcnt(4),
//           XCD-chunked swizzle; epilogue stages tile in LDS (V transposed)
//           so all global stores are 16B coalesced. mode 3 = ctx@Wo+bo -> fp32
//   k_attn: flash attention, QBLK=128 (2 q-frags/wave), K/V double-buffered
//           gload_lds (counted vmcnt), XCD-pinned grid (bh%8), exp2 softmax,
//           MFMA row-sum, setprio around MFMA clusters

#define B_ 8
#define S_ 577
#define H_ 768
#define NH_ 12
#define HD_ 64
#define M_ (B_*S_)     /* 4616 */
#define MPAD 4736      /* 37*128 */
#define BH_ (B_*NH_)   /* 96 */
#define SKPAD 640      /* padded key count */
#define LTS 136        /* padded LDS row stride (shorts) for epilogue tile */

typedef __attribute__((ext_vector_type(8))) short short8;
typedef __attribute__((ext_vector_type(4))) short s16x4;
typedef __attribute__((ext_vector_type(4))) float f32x4;

__device__ inline unsigned short f2bf(float f){
    unsigned int u = __float_as_uint(f);
    u = u + 0x7fffu + ((u>>16)&1u);     // round-to-nearest-even
    return (unsigned short)(u>>16);
}

__device__ inline void gload_lds16(const short* g, short* l){
    __builtin_amdgcn_global_load_lds((const __attribute__((address_space(1))) void*)g,
                                     (__attribute__((address_space(3))) void*)l, 16, 0, 0);
}

// fused prep: blocks [0,1776) cvt | [1776,2352) wt | [2352,2733) pad
__global__ __launch_bounds__(256) void k_prep(
    const float* __restrict__ hs, short* __restrict__ abf,
    const float* __restrict__ Wq, const float* __restrict__ Wk,
    const float* __restrict__ Wv, const float* __restrict__ Wo,
    short* __restrict__ Tq, short* __restrict__ Tk,
    short* __restrict__ Tv, short* __restrict__ To,
    short* __restrict__ kh, short* __restrict__ vt)
{
    const int bid = blockIdx.x, t = threadIdx.x;
    if(bid < 1776){
        // hs fp32 -> bf16, zero rows [4616,4736)
        int i = bid*256 + t;
        if(bid >= 1731){ *(short8*)(abf + (size_t)i*8) = (short8){}; return; }
        const float4* p = (const float4*)(hs + (size_t)i*8);
        float4 a = p[0], b = p[1];
        short8 v;
        v[0]=(short)f2bf(a.x); v[1]=(short)f2bf(a.y); v[2]=(short)f2bf(a.z); v[3]=(short)f2bf(a.w);
        v[4]=(short)f2bf(b.x); v[5]=(short)f2bf(b.y); v[6]=(short)f2bf(b.z); v[7]=(short)f2bf(b.w);
        *(short8*)(abf + (size_t)i*8) = v;
    } else if(bid < 2352){
        // W [k][n] fp32 -> bf16 T [n][k]
        int zidx = bid - 1776;
        int z = zidx & 3, rem = zidx >> 2;        // rem in [0,144)
        int kx = rem % 12, ny = rem / 12;
        const float* W = z==0?Wq: z==1?Wk: z==2?Wv:Wo;
        short*       T = z==0?Tq: z==1?Tk: z==2?Tv:To;
        __shared__ float lds[64][65];
        int k0 = kx*64, n0 = ny*64;
        for(int i=0;i<4;i++){
            int row = i*16 + (t>>4);
            int col = (t&15)*4;
            float4 v = *(const float4*)&W[(k0+row)*768 + n0 + col];
            lds[row][col]=v.x; lds[row][col+1]=v.y; lds[row][col+2]=v.z; lds[row][col+3]=v.w;
        }
        __syncthreads();
        for(int i=0;i<4;i++){
            int n = i*16 + (t>>4);
            int k4 = (t&15)*4;
            for(int j=0;j<4;j++)
                T[(n0+n)*768 + k0 + k4 + j] = (short)f2bf(lds[k4+j][n]);
        }
    } else {
        // zero kh rows [577,640), vt cols [576,640)
        int tid = (bid-2352)*256 + t;
        short8 z = {};
        if(tid < 48384){
            int row_id = tid>>3, ch = tid&7;
            int bh = row_id/63, r = row_id - bh*63;
            *(short8*)&kh[((size_t)bh*SKPAD + 577 + r)*64 + ch*8] = z;
        } else if(tid < 97536){
            int j = tid - 48384;
            int row_id = j>>3, ch = j&7;
            int bh = row_id>>6, d = row_id&63;
            *(short8*)&vt[((size_t)bh*64 + d)*SKPAD + 576 + ch*8] = z;
        }
    }
}

// 128x128 tile GEMM, 512 threads / 8 waves (per-wave 32x64), double-buffered
// counted-vmcnt K-loop, XCD-chunked swizzle.
// mode 0: A[4736][768] @ Tqkv[2304][768]^T -> q/k/v (routed by n-segment)
// mode 3: A=ctx @ To[768][768]^T + bo -> of fp32
__global__ __launch_bounds__(512) void k_gemm(
    const short* __restrict__ A, const short* __restrict__ T,
    const float* __restrict__ b0, const float* __restrict__ b1, const float* __restrict__ b2,
    short* __restrict__ oq, short* __restrict__ ok, short* __restrict__ ovt,
    float* __restrict__ of, int mode, int NT)
{
    __shared__ short sh[32768];            // 64KB: dbuf K-loop; epilogue reuses [0,17408)
    const int t = threadIdx.x;

    // bijective XCD-chunked swizzle (m204): contiguous wg ranges per XCD
    const int nwg = gridDim.x;
    const int q8 = nwg>>3, r8 = nwg&7;
    const int xcd = blockIdx.x&7, cidx = blockIdx.x>>3;
    const int wg = (xcd<r8 ? xcd*(q8+1) : r8*(q8+1) + (xcd-r8)*q8) + cidx;
    const int mt = wg/NT, ntile = wg - mt*NT;
    const int m0 = mt*128, n0 = ntile*128;

    const int seg = (mode==3)? 0 : n0/768;           // block-uniform
    const float* bias = (mode==3)? b0 : (seg==0?b0: seg==1?b1:b2);
    const int nlb = (mode==3)? n0 : n0 - seg*768;

    const int w = t>>6, lane = t&63, g = lane>>4, c = lane&15;
    const int wm = w>>1, wn = w&1;       // wm 0..3 (32-row band), wn 0..1 (64-col half)

    // staging: thread covers rows {w*8+lrow, 64+w*8+lrow}; dest 16B-slot (lane&7);
    // source chunk (lane&7)^(row&7) so LDS[row][slot] = G[row][slot^(row&7)]
    const int lrow = lane>>3;
    const int lcol = ((lane&7) ^ lrow) * 8;
    const short* pa = A + (size_t)(m0 + w*8 + lrow)*768 + lcol;
    const short* pb = T + (size_t)(n0 + w*8 + lrow)*768 + lcol;

    f32x4 acc[2][4] = {};

    // buffers: buf b -> lA at sh+b*16384, lB at sh+b*16384+8192
    #pragma unroll
    for(int i=0;i<2;i++){
        gload_lds16(pa + (size_t)(i*64)*768, &sh[(i*64 + w*8)*64]);
        gload_lds16(pb + (size_t)(i*64)*768, &sh[8192 + (i*64 + w*8)*64]);
    }
    int bb = 0;
    for(int kk=0; kk<12; kk++){
        if(kk<11){
            short* dstA = &sh[(bb^1)*16384];
            short* dstB = dstA + 8192;
            #pragma unroll
            for(int i=0;i<2;i++){
                gload_lds16(pa + (size_t)(i*64)*768 + (kk+1)*64, &dstA[(i*64 + w*8)*64]);
                gload_lds16(pb + (size_t)(i*64)*768 + (kk+1)*64, &dstB[(i*64 + w*8)*64]);
            }
            asm volatile("s_waitcnt vmcnt(4)" ::: "memory");
        } else {
            asm volatile("s_waitcnt vmcnt(0)" ::: "memory");
        }
        __builtin_amdgcn_s_barrier();
        asm volatile("" ::: "memory");

        const short* LA = &sh[bb*16384];
        const short* LB = LA + 8192;
        short8 af[2][2], bfv[4][2];
        #pragma unroll
        for(int mi=0; mi<2; mi++){
            int row = wm*32 + mi*16 + c;
            int rx = (row&7)<<3;
            af[mi][0] = *(const short8*)&LA[row*64 + ((g*8) ^ rx)];
            af[mi][1] = *(const short8*)&LA[row*64 + ((32 + g*8) ^ rx)];
        }
        #pragma unroll
        for(int ni=0; ni<4; ni++){
            int row = wn*64 + ni*16 + c;
            int rx = (row&7)<<3;
            bfv[ni][0] = *(const short8*)&LB[row*64 + ((g*8) ^ rx)];
            bfv[ni][1] = *(const short8*)&LB[row*64 + ((32 + g*8) ^ rx)];
        }
        __builtin_amdgcn_s_setprio(1);
        #pragma unroll
        for(int mi=0; mi<2; mi++)
            #pragma unroll
            for(int ni=0; ni<4; ni++){
                acc[mi][ni] = __builtin_amdgcn_mfma_f32_16x16x32_bf16(af[mi][0], bfv[ni][0], acc[mi][ni], 0,0,0);
                acc[mi][ni] = __builtin_amdgcn_mfma_f32_16x16x32_bf16(af[mi][1], bfv[ni][1], acc[mi][ni], 0,0,0);
            }
        __builtin_amdgcn_s_setprio(0);
        asm volatile("s_waitcnt lgkmcnt(0)" ::: "memory");
        __builtin_amdgcn_s_barrier();
        asm volatile("" ::: "memory");
        bb ^= 1;
    }

    if(mode==3){
        #pragma unroll
        for(int mi=0; mi<2; mi++) for(int ni=0; ni<4; ni++){
            #pragma unroll
            for(int r=0; r<4; r++){
                int m = m0 + wm*32 + mi*16 + g*4 + r;   // C/D: row=(lane>>4)*4+reg
                int n = n0 + wn*64 + ni*16 + c;         // C/D: col=lane&15
                if(m >= M_) continue;
                of[(size_t)m*768 + n] = acc[mi][ni][r] + bias[n];
            }
        }
        return;
    }

    // mode 0 epilogue: stage bf16 tile to LDS (V-segment transposed), then
    // 16B-coalesced stores. LDS tile [128][LTS] reuses the staging buffer.
    if(seg==2){
        #pragma unroll
        for(int mi=0;mi<2;mi++)
            #pragma unroll
            for(int ni=0;ni<4;ni++){
                int nl_ = wn*64 + ni*16 + c;
                float bv = bias[nlb + nl_];
                s16x4 pk;
                #pragma unroll
                for(int r=0;r<4;r++) pk[r] = (short)f2bf(acc[mi][ni][r] + bv);
                int ml0 = wm*32 + mi*16 + g*4;
                *(s16x4*)&sh[nl_*LTS + ml0] = pk;       // transposed: [n][m]
            }
    } else {
        #pragma unroll
        for(int mi=0;mi<2;mi++)
            #pragma unroll
            for(int ni=0;ni<4;ni++){
                int nl_ = wn*64 + ni*16 + c;
                float bv = bias[nlb + nl_];
                #pragma unroll
                for(int r=0;r<4;r++){
                    int ml = wm*32 + mi*16 + g*4 + r;
                    sh[ml*LTS + nl_] = (short)f2bf(acc[mi][ni][r] + bv);
                }
            }
    }
    __syncthreads();

    #pragma unroll
    for(int i=0;i<4;i++){
        int idx = i*512 + t;
        int rp = idx>>4, ch = idx&15;
        short8 v8 = *(const short8*)&sh[rp*LTS + ch*8];
        if(seg==2){
            // rows rp = local d over 2 heads; cols = m (s)
            int nl = nlb + rp, hh = nl>>6, dd = nl&63;
            int mg = m0 + ch*8;
            if(mg < M_){
                int b0_ = mg/S_, s0 = mg - b0_*S_;
                if(s0+7 < S_ && mg+7 < M_){
                    *(short8*)&ovt[(((size_t)b0_*NH_+hh)*HD_+dd)*SKPAD + s0] = v8;
                } else {
                    for(int j=0;j<8;j++){
                        int m=mg+j;
                        if(m<M_){ int bj=m/S_, sj=m-bj*S_;
                            ovt[(((size_t)bj*NH_+hh)*HD_+dd)*SKPAD+sj]=v8[j]; }
                    }
                }
            }
        } else {
            int m = m0 + rp;
            if(m < M_){
                int b0_ = m/S_, s0 = m - b0_*S_;
                int nl = nlb + ch*8, hh = nl>>6, dd = nl&63;
                if(seg==1) *(short8*)&ok[(((size_t)b0_*NH_+hh)*SKPAD + s0)*HD_ + dd] = v8;
                else       *(short8*)&oq[(((size_t)b0_*NH_+hh)*S_   + s0)*HD_ + dd] = v8;
            }
        }
    }
}

// flash attention: QBLK=128 (each wave owns 32 q-rows = 2 fragments), grid (bh, qtile).
// K/V double-buffered via global_load_lds + counted vmcnt; softmax in exp2 domain;
// row-sum via all-ones MFMA; setprio around MFMA clusters.
__global__ __launch_bounds__(256) void k_attn(
    const short* __restrict__ qh, const short* __restrict__ kh, const short* __restrict__ vt,
    short* __restrict__ ctx)
{
    __shared__ short lK[2][64*64], lV[2][64*64], lP[4*2048];
    const int t = threadIdx.x;
    const int w = t>>6, lane = t&63, g = lane>>4, c = lane&15;
    const int bh = blockIdx.x, b = bh/NH_, h = bh%NH_;
    const int q0 = blockIdx.y*128;

    // per-wave Q staging (32 rows) into own lP region (guarded), then frags to regs
    #pragma unroll
    for(int i=0;i<4;i++){
        int row = i*8 + (lane>>3);
        int e8 = (lane&7)*8;
        int s = q0 + w*32 + row;
        short8 v = {};
        if(s < S_) v = *(const short8*)&qh[((size_t)bh*S_ + s)*HD_ + e8];
        *(short8*)&lP[w*2048 + row*64 + (e8 ^ ((row&7)<<3))] = v;
    }
    short8 qf[2][2];
    #pragma unroll
    for(int qi=0; qi<2; qi++)
        #pragma unroll
        for(int ks=0; ks<2; ks++)
            qf[qi][ks] = *(const short8*)&lP[w*2048 + (qi*16+c)*64 + ((ks*32+g*8) ^ ((c&7)<<3))];

    short8 ones;
    #pragma unroll
    for(int j=0;j<8;j++) ones[j] = (short)0x3F80;    // bf16 1.0

    const int srow = lane>>3;
    const int sw8 = ((lane&7) ^ srow)*8;
    const short* pk0 = kh + ((size_t)bh*SKPAD + w*16 + srow)*64 + sw8;
    const short* pv0 = vt + ((size_t)bh*64 + w*16 + srow)*SKPAD + sw8;

    // prologue: stage tile 0 into buffer 0
    #pragma unroll
    for(int i=0;i<2;i++){
        gload_lds16(pk0 + i*8*64,    &lK[0][(w*16+i*8)*64]);
        gload_lds16(pv0 + i*8*SKPAD, &lV[0][(w*16+i*8)*64]);
    }

    float m_run[2][4], l_run[2][4];
    f32x4 O[2][4] = {};
    #pragma unroll
    for(int qi=0;qi<2;qi++)
        #pragma unroll
        for(int r=0;r<4;r++){ m_run[qi][r] = -3e38f; l_run[qi][r] = 0.f; }

    int bb = 0;
    for(int kt=0; kt<10; kt++){
        if(kt<9){
            const short* pk = pk0 + (kt+1)*4096;   // 64 rows * 64
            const short* pv = pv0 + (kt+1)*64;     // 64 cols
            #pragma unroll
            for(int i=0;i<2;i++){
                gload_lds16(pk + i*8*64,    &lK[bb^1][(w*16+i*8)*64]);
                gload_lds16(pv + i*8*SKPAD, &lV[bb^1][(w*16+i*8)*64]);
            }
            asm volatile("s_waitcnt vmcnt(4)" ::: "memory");
        } else {
            asm volatile("s_waitcnt vmcnt(0)" ::: "memory");
        }
        __builtin_amdgcn_s_barrier();
        asm volatile("" ::: "memory");

        const short* LK = lK[bb]; const short* LV = lV[bb];

        // S = Q K^T (per wave: 2 x 16 q-rows x 64 keys), scaled into log2 domain
        float sv[2][4][4];
        #pragma unroll
        for(int nt=0; nt<4; nt++){
            int row = nt*16 + c;
            int rx = (row&7)<<3;
            short8 kf[2];
            kf[0] = *(const short8*)&LK[row*64 + ((g*8) ^ rx)];
            kf[1] = *(const short8*)&LK[row*64 + ((32+g*8) ^ rx)];
            __builtin_amdgcn_s_setprio(1);
            #pragma unroll
            for(int qi=0; qi<2; qi++){
                f32x4 sa = {};
                sa = __builtin_amdgcn_mfma_f32_16x16x32_bf16(qf[qi][0], kf[0], sa, 0,0,0);
                sa = __builtin_amdgcn_mfma_f32_16x16x32_bf16(qf[qi][1], kf[1], sa, 0,0,0);
                #pragma unroll
                for(int r=0;r<4;r++) sv[qi][nt][r] = sa[r]*0.18033688011f;  // /8 * log2(e)
            }
            __builtin_amdgcn_s_setprio(0);
        }
        if(kt==9){
            #pragma unroll
            for(int nt=0; nt<4; nt++){
                int key = 576 + nt*16 + c;
                if(key >= S_){
                    #pragma unroll
                    for(int qi=0;qi<2;qi++)
                        #pragma unroll
                        for(int r=0;r<4;r++) sv[qi][nt][r] = -3e38f;
                }
            }
        }
        // online softmax: max via shuffles (rows on 16 c-lanes), sum via ones-MFMA
        float fac[2][4];
        #pragma unroll
        for(int qi=0; qi<2; qi++)
            #pragma unroll
            for(int r=0;r<4;r++){
                float mx = fmaxf(fmaxf(sv[qi][0][r],sv[qi][1][r]),fmaxf(sv[qi][2][r],sv[qi][3][r]));
                for(int off=1; off<16; off<<=1) mx = fmaxf(mx, __shfl_xor(mx, off));
                float nm = fmaxf(m_run[qi][r], mx);
                fac[qi][r] = __builtin_amdgcn_exp2f(m_run[qi][r] - nm);
                m_run[qi][r] = nm;
            }
        #pragma unroll
        for(int qi=0; qi<2; qi++)
            #pragma unroll
            for(int nt=0; nt<4; nt++)
                #pragma unroll
                for(int r=0;r<4;r++){
                    float p = __builtin_amdgcn_exp2f(sv[qi][nt][r] - m_run[qi][r]);
                    int prow = g*4 + r;
                    lP[w*2048 + qi*1024 + prow*64 + ((nt*16 + c) ^ ((prow&7)<<3))] = (short)f2bf(p);
                }
        // P fragments (own-wave LDS region)
        short8 pf[2][2];
        #pragma unroll
        for(int qi=0; qi<2; qi++)
            #pragma unroll
            for(int ks=0; ks<2; ks++)
                pf[qi][ks] = *(const short8*)&lP[w*2048 + qi*1024 + c*64 + ((ks*32+g*8) ^ ((c&7)<<3))];
        // row-sum = P . 1  (output row = g*4+r matches l_run indexing)
        __builtin_amdgcn_s_setprio(1);
        #pragma unroll
        for(int qi=0; qi<2; qi++){
            f32x4 rs = {};
            rs = __builtin_amdgcn_mfma_f32_16x16x32_bf16(pf[qi][0], ones, rs, 0,0,0);
            rs = __builtin_amdgcn_mfma_f32_16x16x32_bf16(pf[qi][1], ones, rs, 0,0,0);
            #pragma unroll
            for(int r=0;r<4;r++) l_run[qi][r] = l_run[qi][r]*fac[qi][r] + rs[r];
        }
        __builtin_amdgcn_s_setprio(0);
        #pragma unroll
        for(int qi=0; qi<2; qi++)
            #pragma unroll
            for(int nt=0;nt<4;nt++)
                #pragma unroll
                for(int r=0;r<4;r++) O[qi][nt][r] *= fac[qi][r];

        // O += P V  (V^T tile rows = d; vf reused across both q-frags)
        __builtin_amdgcn_s_setprio(1);
        #pragma unroll
        for(int nt=0; nt<4; nt++){
            int vrow = nt*16 + c;
            int rx = (vrow&7)<<3;
            short8 vf[2];
            vf[0] = *(const short8*)&LV[vrow*64 + ((g*8) ^ rx)];
            vf[1] = *(const short8*)&LV[vrow*64 + ((32+g*8) ^ rx)];
            #pragma unroll
            for(int qi=0; qi<2; qi++){
                O[qi][nt] = __builtin_amdgcn_mfma_f32_16x16x32_bf16(pf[qi][0], vf[0], O[qi][nt], 0,0,0);
                O[qi][nt] = __builtin_amdgcn_mfma_f32_16x16x32_bf16(pf[qi][1], vf[1], O[qi][nt], 0,0,0);
            }
        }
        __builtin_amdgcn_s_setprio(0);
        asm volatile("s_waitcnt lgkmcnt(0)" ::: "memory");
        __builtin_amdgcn_s_barrier();
        asm volatile("" ::: "memory");
        bb ^= 1;
    }

    #pragma unroll
    for(int qi=0; qi<2; qi++)
        #pragma unroll
        for(int nt=0; nt<4; nt++)
            #pragma unroll
            for(int r=0;r<4;r++){
                int s = q0 + w*32 + qi*16 + g*4 + r;
                if(s < S_){
                    float val = O[qi][nt][r] / l_run[qi][r];
                    ctx[((size_t)b*S_ + s)*H_ + h*HD_ + nt*16 + c] = (short)f2bf(val);
                }
            }
}

extern "C" void kernel_launch(void* const* d_in, const int* in_sizes, int n_in,
                              void* d_out, int out_size, void* d_ws, size_t ws_size,
                              hipStream_t stream)
{
    const float* hs = (const float*)d_in[0];
    const float* Wq = (const float*)d_in[1];
    const float* bq = (const float*)d_in[2];
    const float* Wk = (const float*)d_in[3];
    const float* bk = (const float*)d_in[4];
    const float* Wv = (const float*)d_in[5];
    const float* bv = (const float*)d_in[6];
    const float* Wo = (const float*)d_in[7];
    const float* bo = (const float*)d_in[8];
    float* out = (float*)d_out;

    char* ws = (char*)d_ws;
    // abf/ctx: 4736*768*2 = 7,274,496
    // Wt x4:   768*768*2  = 1,179,648 each, contiguous -> fused [2304][768] at wqt
    // qh: 96*577*64*2 = 7,090,176 ; kh: 96*640*64*2 = 7,864,320 ; vt: 96*64*640*2 = 7,864,320
    short* abf = (short*)(ws);
    short* ctx = abf;                               // reuse after QKV GEMM
    short* wqt = (short*)(ws + 7274496);
    short* wkt = (short*)(ws + 7274496 + 1179648);
    short* wvt = (short*)(ws + 7274496 + 2*1179648);
    short* wot = (short*)(ws + 7274496 + 3*1179648);
    short* qh  = (short*)(ws + 11993088);
    short* kh  = (short*)(ws + 19083264);
    short* vt  = (short*)(ws + 26947584);
    // total: 34,811,904 B

    k_prep<<<2733, 256, 0, stream>>>(hs, abf, Wq,Wk,Wv,Wo, wqt,wkt,wvt,wot, kh, vt);
    k_gemm<<<666, 512, 0, stream>>>(abf, wqt, bq,bk,bv, qh,kh,vt, nullptr, 0, 18);
    k_attn<<<dim3(96,5), 256, 0, stream>>>(qh, kh, vt, ctx);
    k_gemm<<<222, 512, 0, stream>>>(ctx, wot, bo,bo,bo, nullptr,nullptr,nullptr, out, 3, 6);
}

// Round 16
// 86.085 us; speedup vs baseline: 1.3291x; 1.0322x over previous
//
#include <hip/hip_runtime.h>
#include <hip/hip_bf16.h>

// out = softmax((X Wq + bq)(X Wk + bk)^T / 8) (X Wv + bv) Wo + bo
// All prune/straight-through ops in the reference are value-wise identity.
//
//   k_prep: fused {hs->bf16 A | W^T bf16 x4 | kh/vt pad zero}   (round-6 proven)
//   k_gemm: 128x128 tile, 512 thr / 8 waves, dbuf gload_lds vmcnt(4),
//           XCD-chunked swizzle, LDS-staged coalesced epilogue  (round-6 proven)
//   k_attn: flash attention, QBLK=128 AND KVBLK=128 (5 key-iterations, half the
//           barrier/vmcnt events of round-6), K/V double-buffered gload_lds
//           (counted vmcnt(8)), per-qi softmax (register pressure), exp2 domain,
//           MFMA row-sum, setprio. LDS 80KB -> 2 blocks/CU.

#define B_ 8
#define S_ 577
#define H_ 768
#define NH_ 12
#define HD_ 64
#define M_ (B_*S_)     /* 4616 */
#define MPAD 4736
#define BH_ (B_*NH_)   /* 96 */
#define SKPAD 640      /* padded key count */
#define LTS 136        /* padded LDS row stride (shorts) for epilogue tile */

typedef __attribute__((ext_vector_type(8))) short short8;
typedef __attribute__((ext_vector_type(4))) short s16x4;
typedef __attribute__((ext_vector_type(4))) float f32x4;

__device__ inline unsigned short f2bf(float f){
    unsigned int u = __float_as_uint(f);
    u = u + 0x7fffu + ((u>>16)&1u);     // round-to-nearest-even
    return (unsigned short)(u>>16);
}

__device__ inline void gload_lds16(const short* g, short* l){
    __builtin_amdgcn_global_load_lds((const __attribute__((address_space(1))) void*)g,
                                     (__attribute__((address_space(3))) void*)l, 16, 0, 0);
}

// fused prep: blocks [0,1776) cvt | [1776,2352) wt | [2352,2733) pad
__global__ __launch_bounds__(256) void k_prep(
    const float* __restrict__ hs, short* __restrict__ abf,
    const float* __restrict__ Wq, const float* __restrict__ Wk,
    const float* __restrict__ Wv, const float* __restrict__ Wo,
    short* __restrict__ Tq, short* __restrict__ Tk,
    short* __restrict__ Tv, short* __restrict__ To,
    short* __restrict__ kh, short* __restrict__ vt)
{
    const int bid = blockIdx.x, t = threadIdx.x;
    if(bid < 1776){
        int i = bid*256 + t;
        if(bid >= 1731){ *(short8*)(abf + (size_t)i*8) = (short8){}; return; }
        const float4* p = (const float4*)(hs + (size_t)i*8);
        float4 a = p[0], b = p[1];
        short8 v;
        v[0]=(short)f2bf(a.x); v[1]=(short)f2bf(a.y); v[2]=(short)f2bf(a.z); v[3]=(short)f2bf(a.w);
        v[4]=(short)f2bf(b.x); v[5]=(short)f2bf(b.y); v[6]=(short)f2bf(b.z); v[7]=(short)f2bf(b.w);
        *(short8*)(abf + (size_t)i*8) = v;
    } else if(bid < 2352){
        int zidx = bid - 1776;
        int z = zidx & 3, rem = zidx >> 2;
        int kx = rem % 12, ny = rem / 12;
        const float* W = z==0?Wq: z==1?Wk: z==2?Wv:Wo;
        short*       T = z==0?Tq: z==1?Tk: z==2?Tv:To;
        __shared__ float lds[64][65];
        int k0 = kx*64, n0 = ny*64;
        for(int i=0;i<4;i++){
            int row = i*16 + (t>>4);
            int col = (t&15)*4;
            float4 v = *(const float4*)&W[(k0+row)*768 + n0 + col];
            lds[row][col]=v.x; lds[row][col+1]=v.y; lds[row][col+2]=v.z; lds[row][col+3]=v.w;
        }
        __syncthreads();
        for(int i=0;i<4;i++){
            int n = i*16 + (t>>4);
            int k4 = (t&15)*4;
            for(int j=0;j<4;j++)
                T[(n0+n)*768 + k0 + k4 + j] = (short)f2bf(lds[k4+j][n]);
        }
    } else {
        int tid = (bid-2352)*256 + t;
        short8 z = {};
        if(tid < 48384){
            int row_id = tid>>3, ch = tid&7;
            int bh = row_id/63, r = row_id - bh*63;
            *(short8*)&kh[((size_t)bh*SKPAD + 577 + r)*64 + ch*8] = z;
        } else if(tid < 97536){
            int j = tid - 48384;
            int row_id = j>>3, ch = j&7;
            int bh = row_id>>6, d = row_id&63;
            *(short8*)&vt[((size_t)bh*64 + d)*SKPAD + 576 + ch*8] = z;
        }
    }
}

// 128x128 tile GEMM, 512 threads / 8 waves, double-buffered counted-vmcnt K-loop,
// XCD-chunked swizzle. mode 0: QKV fused; mode 3: ctx@Wo+bo -> fp32  (round-6)
__global__ __launch_bounds__(512) void k_gemm(
    const short* __restrict__ A, const short* __restrict__ T,
    const float* __restrict__ b0, const float* __restrict__ b1, const float* __restrict__ b2,
    short* __restrict__ oq, short* __restrict__ ok, short* __restrict__ ovt,
    float* __restrict__ of, int mode, int NT)
{
    __shared__ short sh[32768];            // 64KB: dbuf K-loop; epilogue reuses [0,17408)
    const int t = threadIdx.x;

    const int nwg = gridDim.x;
    const int q8 = nwg>>3, r8 = nwg&7;
    const int xcd = blockIdx.x&7, cidx = blockIdx.x>>3;
    const int wg = (xcd<r8 ? xcd*(q8+1) : r8*(q8+1) + (xcd-r8)*q8) + cidx;
    const int mt = wg/NT, ntile = wg - mt*NT;
    const int m0 = mt*128, n0 = ntile*128;

    const int seg = (mode==3)? 0 : n0/768;
    const float* bias = (mode==3)? b0 : (seg==0?b0: seg==1?b1:b2);
    const int nlb = (mode==3)? n0 : n0 - seg*768;

    const int w = t>>6, lane = t&63, g = lane>>4, c = lane&15;
    const int wm = w>>1, wn = w&1;

    const int lrow = lane>>3;
    const int lcol = ((lane&7) ^ lrow) * 8;
    const short* pa = A + (size_t)(m0 + w*8 + lrow)*768 + lcol;
    const short* pb = T + (size_t)(n0 + w*8 + lrow)*768 + lcol;

    f32x4 acc[2][4] = {};

    #pragma unroll
    for(int i=0;i<2;i++){
        gload_lds16(pa + (size_t)(i*64)*768, &sh[(i*64 + w*8)*64]);
        gload_lds16(pb + (size_t)(i*64)*768, &sh[8192 + (i*64 + w*8)*64]);
    }
    int bb = 0;
    for(int kk=0; kk<12; kk++){
        if(kk<11){
            short* dstA = &sh[(bb^1)*16384];
            short* dstB = dstA + 8192;
            #pragma unroll
            for(int i=0;i<2;i++){
                gload_lds16(pa + (size_t)(i*64)*768 + (kk+1)*64, &dstA[(i*64 + w*8)*64]);
                gload_lds16(pb + (size_t)(i*64)*768 + (kk+1)*64, &dstB[(i*64 + w*8)*64]);
            }
            asm volatile("s_waitcnt vmcnt(4)" ::: "memory");
        } else {
            asm volatile("s_waitcnt vmcnt(0)" ::: "memory");
        }
        __builtin_amdgcn_s_barrier();
        asm volatile("" ::: "memory");

        const short* LA = &sh[bb*16384];
        const short* LB = LA + 8192;
        short8 af[2][2], bfv[4][2];
        #pragma unroll
        for(int mi=0; mi<2; mi++){
            int row = wm*32 + mi*16 + c;
            int rx = (row&7)<<3;
            af[mi][0] = *(const short8*)&LA[row*64 + ((g*8) ^ rx)];
            af[mi][1] = *(const short8*)&LA[row*64 + ((32 + g*8) ^ rx)];
        }
        #pragma unroll
        for(int ni=0; ni<4; ni++){
            int row = wn*64 + ni*16 + c;
            int rx = (row&7)<<3;
            bfv[ni][0] = *(const short8*)&LB[row*64 + ((g*8) ^ rx)];
            bfv[ni][1] = *(const short8*)&LB[row*64 + ((32 + g*8) ^ rx)];
        }
        __builtin_amdgcn_s_setprio(1);
        #pragma unroll
        for(int mi=0; mi<2; mi++)
            #pragma unroll
            for(int ni=0; ni<4; ni++){
                acc[mi][ni] = __builtin_amdgcn_mfma_f32_16x16x32_bf16(af[mi][0], bfv[ni][0], acc[mi][ni], 0,0,0);
                acc[mi][ni] = __builtin_amdgcn_mfma_f32_16x16x32_bf16(af[mi][1], bfv[ni][1], acc[mi][ni], 0,0,0);
            }
        __builtin_amdgcn_s_setprio(0);
        asm volatile("s_waitcnt lgkmcnt(0)" ::: "memory");
        __builtin_amdgcn_s_barrier();
        asm volatile("" ::: "memory");
        bb ^= 1;
    }

    if(mode==3){
        #pragma unroll
        for(int mi=0; mi<2; mi++) for(int ni=0; ni<4; ni++){
            #pragma unroll
            for(int r=0; r<4; r++){
                int m = m0 + wm*32 + mi*16 + g*4 + r;
                int n = n0 + wn*64 + ni*16 + c;
                if(m >= M_) continue;
                of[(size_t)m*768 + n] = acc[mi][ni][r] + bias[n];
            }
        }
        return;
    }

    if(seg==2){
        #pragma unroll
        for(int mi=0;mi<2;mi++)
            #pragma unroll
            for(int ni=0;ni<4;ni++){
                int nl_ = wn*64 + ni*16 + c;
                float bv = bias[nlb + nl_];
                s16x4 pk;
                #pragma unroll
                for(int r=0;r<4;r++) pk[r] = (short)f2bf(acc[mi][ni][r] + bv);
                int ml0 = wm*32 + mi*16 + g*4;
                *(s16x4*)&sh[nl_*LTS + ml0] = pk;       // transposed: [n][m]
            }
    } else {
        #pragma unroll
        for(int mi=0;mi<2;mi++)
            #pragma unroll
            for(int ni=0;ni<4;ni++){
                int nl_ = wn*64 + ni*16 + c;
                float bv = bias[nlb + nl_];
                #pragma unroll
                for(int r=0;r<4;r++){
                    int ml = wm*32 + mi*16 + g*4 + r;
                    sh[ml*LTS + nl_] = (short)f2bf(acc[mi][ni][r] + bv);
                }
            }
    }
    __syncthreads();

    #pragma unroll
    for(int i=0;i<4;i++){
        int idx = i*512 + t;
        int rp = idx>>4, ch = idx&15;
        short8 v8 = *(const short8*)&sh[rp*LTS + ch*8];
        if(seg==2){
            int nl = nlb + rp, hh = nl>>6, dd = nl&63;
            int mg = m0 + ch*8;
            if(mg < M_){
                int b0_ = mg/S_, s0 = mg - b0_*S_;
                if(s0+7 < S_ && mg+7 < M_){
                    *(short8*)&ovt[(((size_t)b0_*NH_+hh)*HD_+dd)*SKPAD + s0] = v8;
                } else {
                    for(int j=0;j<8;j++){
                        int m=mg+j;
                        if(m<M_){ int bj=m/S_, sj=m-bj*S_;
                            ovt[(((size_t)bj*NH_+hh)*HD_+dd)*SKPAD+sj]=v8[j]; }
                    }
                }
            }
        } else {
            int m = m0 + rp;
            if(m < M_){
                int b0_ = m/S_, s0 = m - b0_*S_;
                int nl = nlb + ch*8, hh = nl>>6, dd = nl&63;
                if(seg==1) *(short8*)&ok[(((size_t)b0_*NH_+hh)*SKPAD + s0)*HD_ + dd] = v8;
                else       *(short8*)&oq[(((size_t)b0_*NH_+hh)*S_   + s0)*HD_ + dd] = v8;
            }
        }
    }
}

// flash attention: QBLK=128, KVBLK=128 (5 key-iterations), K/V double-buffered
// gload_lds + counted vmcnt(8); per-qi softmax; exp2 domain; MFMA row-sum; setprio.
__global__ __launch_bounds__(256) void k_attn(
    const short* __restrict__ qh, const short* __restrict__ kh, const short* __restrict__ vt,
    short* __restrict__ ctx)
{
    __shared__ short lK[2][128*64], lV[2][64*128], lP[4*2048];
    const int t = threadIdx.x;
    const int w = t>>6, lane = t&63, g = lane>>4, c = lane&15;
    const int bh = blockIdx.x, b = bh/NH_, h = bh%NH_;
    const int q0 = blockIdx.y*128;

    // per-wave Q staging (32 rows) into own lP region, then frags to regs
    #pragma unroll
    for(int i=0;i<4;i++){
        int row = i*8 + (lane>>3);
        int e8 = (lane&7)*8;
        int s = q0 + w*32 + row;
        short8 v = {};
        if(s < S_) v = *(const short8*)&qh[((size_t)bh*S_ + s)*HD_ + e8];
        *(short8*)&lP[w*2048 + row*64 + (e8 ^ ((row&7)<<3))] = v;
    }
    short8 qf[2][2];
    #pragma unroll
    for(int qi=0; qi<2; qi++)
        #pragma unroll
        for(int ks=0; ks<2; ks++)
            qf[qi][ks] = *(const short8*)&lP[w*2048 + (qi*16+c)*64 + ((ks*32+g*8) ^ ((c&7)<<3))];

    short8 ones;
    #pragma unroll
    for(int j=0;j<8;j++) ones[j] = (short)0x3F80;    // bf16 1.0

    // staging maps (KVBLK=128): 4 K-chunks + 4 V-chunks per thread per tile
    const short* pk[4]; const short* pv[4]; int dk[4], dv[4];
    #pragma unroll
    for(int i=0;i<4;i++){
        int id = i*256 + t;
        int krow = id>>3, kch = id&7;            // 128 rows x 8 chunks
        pk[i] = kh + ((size_t)bh*SKPAD + krow)*64 + (kch ^ (krow&7))*8;
        dk[i] = krow*64 + kch*8;
        int vd = id>>4, vch = id&15;             // 64 d-rows x 16 chunks
        pv[i] = vt + ((size_t)bh*64 + vd)*SKPAD + (vch ^ (vd&7))*8;
        dv[i] = vd*128 + vch*8;
    }
    #define STAGE(kt) { _Pragma("unroll") for(int i_=0;i_<4;i_++){           \
        gload_lds16(pk[i_] + (size_t)(kt)*8192, &lK[(kt)&1][dk[i_]]);        \
        gload_lds16(pv[i_] + (kt)*128,          &lV[(kt)&1][dv[i_]]); } }

    STAGE(0);

    float m_run[2][4], l_run[2][4];
    f32x4 O[2][4] = {};
    #pragma unroll
    for(int qi=0;qi<2;qi++)
        #pragma unroll
        for(int r=0;r<4;r++){ m_run[qi][r] = -3e38f; l_run[qi][r] = 0.f; }

    for(int kt=0; kt<5; kt++){
        if(kt<4){
            STAGE(kt+1);
            asm volatile("s_waitcnt vmcnt(8)" ::: "memory");   // tile kt complete
        } else {
            asm volatile("s_waitcnt vmcnt(0)" ::: "memory");
        }
        __builtin_amdgcn_s_barrier();
        asm volatile("" ::: "memory");

        const short* LK = lK[kt&1]; const short* LV = lV[kt&1];

        #pragma unroll
        for(int qi=0; qi<2; qi++){
            // S = Q K^T: 16 q-rows x 128 keys (D row = q-row g*4+r, col = key c)
            float sv[8][4];
            #pragma unroll
            for(int nt=0; nt<8; nt++){
                int row = nt*16 + c;
                int rx = (row&7)<<3;
                short8 kf0 = *(const short8*)&LK[row*64 + ((g*8) ^ rx)];
                short8 kf1 = *(const short8*)&LK[row*64 + ((32+g*8) ^ rx)];
                __builtin_amdgcn_s_setprio(1);
                f32x4 sa = {};
                sa = __builtin_amdgcn_mfma_f32_16x16x32_bf16(qf[qi][0], kf0, sa, 0,0,0);
                sa = __builtin_amdgcn_mfma_f32_16x16x32_bf16(qf[qi][1], kf1, sa, 0,0,0);
                __builtin_amdgcn_s_setprio(0);
                #pragma unroll
                for(int r=0;r<4;r++) sv[nt][r] = sa[r]*0.18033688011f;  // /8 * log2(e)
            }
            if(kt==4){
                #pragma unroll
                for(int nt=0; nt<8; nt++){
                    int key = 512 + nt*16 + c;
                    if(key >= S_){
                        #pragma unroll
                        for(int r=0;r<4;r++) sv[nt][r] = -3e38f;
                    }
                }
            }
            float fac[4];
            #pragma unroll
            for(int r=0;r<4;r++){
                float mx = sv[0][r];
                #pragma unroll
                for(int nt=1;nt<8;nt++) mx = fmaxf(mx, sv[nt][r]);
                for(int off=1; off<16; off<<=1) mx = fmaxf(mx, __shfl_xor(mx, off));
                float nm = fmaxf(m_run[qi][r], mx);
                fac[r] = __builtin_amdgcn_exp2f(m_run[qi][r] - nm);
                m_run[qi][r] = nm;
            }
            #pragma unroll
            for(int nt=0; nt<8; nt++)
                #pragma unroll
                for(int r=0;r<4;r++){
                    float p = __builtin_amdgcn_exp2f(sv[nt][r] - m_run[qi][r]);
                    int prow = g*4 + r;
                    lP[w*2048 + prow*128 + ((nt*16 + c) ^ ((prow&7)<<3))] = (short)f2bf(p);
                }
            // P fragments (own-wave region; WAR across qi handled by lgkm deps)
            short8 pf[4];
            #pragma unroll
            for(int ks=0; ks<4; ks++)
                pf[ks] = *(const short8*)&lP[w*2048 + c*128 + ((ks*32+g*8) ^ ((c&7)<<3))];
            // row-sum = P . 1
            __builtin_amdgcn_s_setprio(1);
            f32x4 rs = {};
            #pragma unroll
            for(int ks=0; ks<4; ks++)
                rs = __builtin_amdgcn_mfma_f32_16x16x32_bf16(pf[ks], ones, rs, 0,0,0);
            __builtin_amdgcn_s_setprio(0);
            #pragma unroll
            for(int r=0;r<4;r++) l_run[qi][r] = l_run[qi][r]*fac[r] + rs[r];
            #pragma unroll
            for(int nt=0;nt<4;nt++)
                #pragma unroll
                for(int r=0;r<4;r++) O[qi][nt][r] *= fac[r];

            // O += P V (V^T tile rows = d, 128-key row)
            __builtin_amdgcn_s_setprio(1);
            #pragma unroll
            for(int nt=0; nt<4; nt++){
                int vrow = nt*16 + c;
                int rx = (vrow&7)<<3;
                #pragma unroll
                for(int ks=0; ks<4; ks++){
                    short8 vf = *(const short8*)&LV[vrow*128 + ((ks*32+g*8) ^ rx)];
                    O[qi][nt] = __builtin_amdgcn_mfma_f32_16x16x32_bf16(pf[ks], vf, O[qi][nt], 0,0,0);
                }
            }
            __builtin_amdgcn_s_setprio(0);
        }
        asm volatile("s_waitcnt lgkmcnt(0)" ::: "memory");
        __builtin_amdgcn_s_barrier();
        asm volatile("" ::: "memory");
    }
    #undef STAGE

    #pragma unroll
    for(int qi=0; qi<2; qi++)
        #pragma unroll
        for(int nt=0; nt<4; nt++)
            #pragma unroll
            for(int r=0;r<4;r++){
                int s = q0 + w*32 + qi*16 + g*4 + r;
                if(s < S_){
                    float val = O[qi][nt][r] / l_run[qi][r];
                    ctx[((size_t)b*S_ + s)*H_ + h*HD_ + nt*16 + c] = (short)f2bf(val);
                }
            }
}

extern "C" void kernel_launch(void* const* d_in, const int* in_sizes, int n_in,
                              void* d_out, int out_size, void* d_ws, size_t ws_size,
                              hipStream_t stream)
{
    const float* hs = (const float*)d_in[0];
    const float* Wq = (const float*)d_in[1];
    const float* bq = (const float*)d_in[2];
    const float* Wk = (const float*)d_in[3];
    const float* bk = (const float*)d_in[4];
    const float* Wv = (const float*)d_in[5];
    const float* bv = (const float*)d_in[6];
    const float* Wo = (const float*)d_in[7];
    const float* bo = (const float*)d_in[8];
    float* out = (float*)d_out;

    char* ws = (char*)d_ws;
    short* abf = (short*)(ws);
    short* ctx = abf;                               // reuse after QKV GEMM
    short* wqt = (short*)(ws + 7274496);
    short* wkt = (short*)(ws + 7274496 + 1179648);
    short* wvt = (short*)(ws + 7274496 + 2*1179648);
    short* wot = (short*)(ws + 7274496 + 3*1179648);
    short* qh  = (short*)(ws + 11993088);
    short* kh  = (short*)(ws + 19083264);
    short* vt  = (short*)(ws + 26947584);
    // total: 34,811,904 B

    k_prep<<<2733, 256, 0, stream>>>(hs, abf, Wq,Wk,Wv,Wo, wqt,wkt,wvt,wot, kh, vt);
    k_gemm<<<666, 512, 0, stream>>>(abf, wqt, bq,bk,bv, qh,kh,vt, nullptr, 0, 18);
    k_attn<<<dim3(96,5), 256, 0, stream>>>(qh, kh, vt, ctx);
    k_gemm<<<222, 512, 0, stream>>>(ctx, wot, bo,bo,bo, nullptr,nullptr,nullptr, out, 3, 6);
}

// Round 17
// 83.624 us; speedup vs baseline: 1.3682x; 1.0294x over previous
//
#include <hip/hip_runtime.h>
#include <hip/hip_bf16.h>

// out = softmax((X Wq + bq)(X Wk + bk)^T / 8) (X Wv + bv) Wo + bo
// All prune/straight-through ops in the reference are value-wise identity.
//
//   k_prep: fused {hs->bf16 A | W^T bf16 x4 | kh/vt pad zero}   (round-6 proven)
//   k_gemm: 128x128 tile, 512 thr / 8 waves, BK=32, THREE LDS slots (48KB),
//           ONE barrier per K-step (3-slot rotation makes single-barrier
//           race-free; bounded 1-iter wave slip), counted vmcnt(2);
//           XCD-chunked swizzle, LDS-staged coalesced epilogue.
//   k_attn: flash attention, QBLK=128/KVBLK=128 (round-16 proven: 5 key-iters,
//           dbuf gload_lds vmcnt(8), per-qi softmax, exp2, MFMA row-sum, setprio)

#define B_ 8
#define S_ 577
#define H_ 768
#define NH_ 12
#define HD_ 64
#define M_ (B_*S_)     /* 4616 */
#define MPAD 4736
#define BH_ (B_*NH_)   /* 96 */
#define SKPAD 640      /* padded key count */
#define LTS 136        /* padded LDS row stride (shorts) for epilogue tile */

typedef __attribute__((ext_vector_type(8))) short short8;
typedef __attribute__((ext_vector_type(4))) short s16x4;
typedef __attribute__((ext_vector_type(4))) float f32x4;

__device__ inline unsigned short f2bf(float f){
    unsigned int u = __float_as_uint(f);
    u = u + 0x7fffu + ((u>>16)&1u);     // round-to-nearest-even
    return (unsigned short)(u>>16);
}

__device__ inline void gload_lds16(const short* g, short* l){
    __builtin_amdgcn_global_load_lds((const __attribute__((address_space(1))) void*)g,
                                     (__attribute__((address_space(3))) void*)l, 16, 0, 0);
}

// fused prep: blocks [0,1776) cvt | [1776,2352) wt | [2352,2733) pad
__global__ __launch_bounds__(256) void k_prep(
    const float* __restrict__ hs, short* __restrict__ abf,
    const float* __restrict__ Wq, const float* __restrict__ Wk,
    const float* __restrict__ Wv, const float* __restrict__ Wo,
    short* __restrict__ Tq, short* __restrict__ Tk,
    short* __restrict__ Tv, short* __restrict__ To,
    short* __restrict__ kh, short* __restrict__ vt)
{
    const int bid = blockIdx.x, t = threadIdx.x;
    if(bid < 1776){
        int i = bid*256 + t;
        if(bid >= 1731){ *(short8*)(abf + (size_t)i*8) = (short8){}; return; }
        const float4* p = (const float4*)(hs + (size_t)i*8);
        float4 a = p[0], b = p[1];
        short8 v;
        v[0]=(short)f2bf(a.x); v[1]=(short)f2bf(a.y); v[2]=(short)f2bf(a.z); v[3]=(short)f2bf(a.w);
        v[4]=(short)f2bf(b.x); v[5]=(short)f2bf(b.y); v[6]=(short)f2bf(b.z); v[7]=(short)f2bf(b.w);
        *(short8*)(abf + (size_t)i*8) = v;
    } else if(bid < 2352){
        int zidx = bid - 1776;
        int z = zidx & 3, rem = zidx >> 2;
        int kx = rem % 12, ny = rem / 12;
        const float* W = z==0?Wq: z==1?Wk: z==2?Wv:Wo;
        short*       T = z==0?Tq: z==1?Tk: z==2?Tv:To;
        __shared__ float lds[64][65];
        int k0 = kx*64, n0 = ny*64;
        for(int i=0;i<4;i++){
            int row = i*16 + (t>>4);
            int col = (t&15)*4;
            float4 v = *(const float4*)&W[(k0+row)*768 + n0 + col];
            lds[row][col]=v.x; lds[row][col+1]=v.y; lds[row][col+2]=v.z; lds[row][col+3]=v.w;
        }
        __syncthreads();
        for(int i=0;i<4;i++){
            int n = i*16 + (t>>4);
            int k4 = (t&15)*4;
            for(int j=0;j<4;j++)
                T[(n0+n)*768 + k0 + k4 + j] = (short)f2bf(lds[k4+j][n]);
        }
    } else {
        int tid = (bid-2352)*256 + t;
        short8 z = {};
        if(tid < 48384){
            int row_id = tid>>3, ch = tid&7;
            int bh = row_id/63, r = row_id - bh*63;
            *(short8*)&kh[((size_t)bh*SKPAD + 577 + r)*64 + ch*8] = z;
        } else if(tid < 97536){
            int j = tid - 48384;
            int row_id = j>>3, ch = j&7;
            int bh = row_id>>6, d = row_id&63;
            *(short8*)&vt[((size_t)bh*64 + d)*SKPAD + 576 + ch*8] = z;
        }
    }
}

// 128x128 tile GEMM, 512 threads / 8 waves, BK=32, 3-slot single-barrier K-loop.
// mode 0: A[4736][768] @ Tqkv[2304][768]^T -> q/k/v ; mode 3: ctx@Wo+bo -> fp32
__global__ __launch_bounds__(512) void k_gemm(
    const short* __restrict__ A, const short* __restrict__ T,
    const float* __restrict__ b0, const float* __restrict__ b1, const float* __restrict__ b2,
    short* __restrict__ oq, short* __restrict__ ok, short* __restrict__ ovt,
    float* __restrict__ of, int mode, int NT)
{
    __shared__ short sh[24576];            // 48KB: 3 slots x (A 8KB | B 8KB); epi 34816B fits
    const int t = threadIdx.x;

    const int nwg = gridDim.x;
    const int q8 = nwg>>3, r8 = nwg&7;
    const int xcd = blockIdx.x&7, cidx = blockIdx.x>>3;
    const int wg = (xcd<r8 ? xcd*(q8+1) : r8*(q8+1) + (xcd-r8)*q8) + cidx;
    const int mt = wg/NT, ntile = wg - mt*NT;
    const int m0 = mt*128, n0 = ntile*128;

    const int seg = (mode==3)? 0 : n0/768;
    const float* bias = (mode==3)? b0 : (seg==0?b0: seg==1?b1:b2);
    const int nlb = (mode==3)? n0 : n0 - seg*768;

    const int w = t>>6, lane = t&63, g = lane>>4, c = lane&15;
    const int wm = w>>1, wn = w&1;

    // staging (BK=32): thread t covers row t>>2, 16B-chunk t&3; source chunk
    // (t&3) ^ ((row>>1)&3) so LDS[row][ch] = G[row][ch ^ ((row>>1)&3)]
    const int srow = t>>2, sch = t&3;
    const short* gA = A + (size_t)(m0 + srow)*768 + (sch ^ ((srow>>1)&3))*8;
    const short* gB = T + (size_t)(n0 + srow)*768 + (sch ^ ((srow>>1)&3))*8;
    const int dA = srow*32 + sch*8;
    const int dB = 4096 + dA;

    #define SLOT(k) (((k)%3)*8192)
    #define ISS(k) { gload_lds16(gA + (k)*32, &sh[SLOT(k)+dA]); \
                     gload_lds16(gB + (k)*32, &sh[SLOT(k)+dB]); }

    f32x4 acc[2][4] = {};

    // prologue: stage tiles 0,1; counted wait for tile 0
    ISS(0); ISS(1);
    asm volatile("s_waitcnt vmcnt(2)" ::: "memory");
    __builtin_amdgcn_s_barrier();
    asm volatile("" ::: "memory");

    for(int kt=0; kt<24; kt++){
        const short* LA = &sh[SLOT(kt)];
        const short* LB = LA + 4096;
        short8 af[2], bf[4];
        #pragma unroll
        for(int mi=0; mi<2; mi++){
            int row = wm*32 + mi*16 + c;
            af[mi] = *(const short8*)&LA[row*32 + ((g ^ ((row>>1)&3))<<3)];
        }
        #pragma unroll
        for(int ni=0; ni<4; ni++){
            int row = wn*64 + ni*16 + c;
            bf[ni] = *(const short8*)&LB[row*32 + ((g ^ ((row>>1)&3))<<3)];
        }
        if(kt<22) ISS(kt+2);
        asm volatile("s_waitcnt lgkmcnt(0)" ::: "memory");
        __builtin_amdgcn_s_setprio(1);
        #pragma unroll
        for(int mi=0; mi<2; mi++)
            #pragma unroll
            for(int ni=0; ni<4; ni++)
                acc[mi][ni] = __builtin_amdgcn_mfma_f32_16x16x32_bf16(af[mi], bf[ni], acc[mi][ni], 0,0,0);
        __builtin_amdgcn_s_setprio(0);
        if(kt<23){
            if(kt<22){ asm volatile("s_waitcnt vmcnt(2)" ::: "memory"); }
            else     { asm volatile("s_waitcnt vmcnt(0)" ::: "memory"); }
            __builtin_amdgcn_s_barrier();
            asm volatile("" ::: "memory");
        }
    }
    #undef SLOT
    #undef ISS

    if(mode==3){
        #pragma unroll
        for(int mi=0; mi<2; mi++) for(int ni=0; ni<4; ni++){
            #pragma unroll
            for(int r=0; r<4; r++){
                int m = m0 + wm*32 + mi*16 + g*4 + r;   // C/D: row=(lane>>4)*4+reg
                int n = n0 + wn*64 + ni*16 + c;         // C/D: col=lane&15
                if(m >= M_) continue;
                of[(size_t)m*768 + n] = acc[mi][ni][r] + bias[n];
            }
        }
        return;
    }

    __syncthreads();   // all reads of sh done before epilogue overwrite

    if(seg==2){
        #pragma unroll
        for(int mi=0;mi<2;mi++)
            #pragma unroll
            for(int ni=0;ni<4;ni++){
                int nl_ = wn*64 + ni*16 + c;
                float bv = bias[nlb + nl_];
                s16x4 pk;
                #pragma unroll
                for(int r=0;r<4;r++) pk[r] = (short)f2bf(acc[mi][ni][r] + bv);
                int ml0 = wm*32 + mi*16 + g*4;
                *(s16x4*)&sh[nl_*LTS + ml0] = pk;       // transposed: [n][m]
            }
    } else {
        #pragma unroll
        for(int mi=0;mi<2;mi++)
            #pragma unroll
            for(int ni=0;ni<4;ni++){
                int nl_ = wn*64 + ni*16 + c;
                float bv = bias[nlb + nl_];
                #pragma unroll
                for(int r=0;r<4;r++){
                    int ml = wm*32 + mi*16 + g*4 + r;
                    sh[ml*LTS + nl_] = (short)f2bf(acc[mi][ni][r] + bv);
                }
            }
    }
    __syncthreads();

    #pragma unroll
    for(int i=0;i<4;i++){
        int idx = i*512 + t;
        int rp = idx>>4, ch = idx&15;
        short8 v8 = *(const short8*)&sh[rp*LTS + ch*8];
        if(seg==2){
            int nl = nlb + rp, hh = nl>>6, dd = nl&63;
            int mg = m0 + ch*8;
            if(mg < M_){
                int b0_ = mg/S_, s0 = mg - b0_*S_;
                if(s0+7 < S_ && mg+7 < M_){
                    *(short8*)&ovt[(((size_t)b0_*NH_+hh)*HD_+dd)*SKPAD + s0] = v8;
                } else {
                    for(int j=0;j<8;j++){
                        int m=mg+j;
                        if(m<M_){ int bj=m/S_, sj=m-bj*S_;
                            ovt[(((size_t)bj*NH_+hh)*HD_+dd)*SKPAD+sj]=v8[j]; }
                    }
                }
            }
        } else {
            int m = m0 + rp;
            if(m < M_){
                int b0_ = m/S_, s0 = m - b0_*S_;
                int nl = nlb + ch*8, hh = nl>>6, dd = nl&63;
                if(seg==1) *(short8*)&ok[(((size_t)b0_*NH_+hh)*SKPAD + s0)*HD_ + dd] = v8;
                else       *(short8*)&oq[(((size_t)b0_*NH_+hh)*S_   + s0)*HD_ + dd] = v8;
            }
        }
    }
}

// flash attention: QBLK=128, KVBLK=128 (5 key-iterations), K/V double-buffered
// gload_lds + counted vmcnt(8); per-qi softmax; exp2 domain; MFMA row-sum; setprio.
__global__ __launch_bounds__(256) void k_attn(
    const short* __restrict__ qh, const short* __restrict__ kh, const short* __restrict__ vt,
    short* __restrict__ ctx)
{
    __shared__ short lK[2][128*64], lV[2][64*128], lP[4*2048];
    const int t = threadIdx.x;
    const int w = t>>6, lane = t&63, g = lane>>4, c = lane&15;
    const int bh = blockIdx.x, b = bh/NH_, h = bh%NH_;
    const int q0 = blockIdx.y*128;

    // per-wave Q staging (32 rows) into own lP region, then frags to regs
    #pragma unroll
    for(int i=0;i<4;i++){
        int row = i*8 + (lane>>3);
        int e8 = (lane&7)*8;
        int s = q0 + w*32 + row;
        short8 v = {};
        if(s < S_) v = *(const short8*)&qh[((size_t)bh*S_ + s)*HD_ + e8];
        *(short8*)&lP[w*2048 + row*64 + (e8 ^ ((row&7)<<3))] = v;
    }
    short8 qf[2][2];
    #pragma unroll
    for(int qi=0; qi<2; qi++)
        #pragma unroll
        for(int ks=0; ks<2; ks++)
            qf[qi][ks] = *(const short8*)&lP[w*2048 + (qi*16+c)*64 + ((ks*32+g*8) ^ ((c&7)<<3))];

    short8 ones;
    #pragma unroll
    for(int j=0;j<8;j++) ones[j] = (short)0x3F80;    // bf16 1.0

    // staging maps (KVBLK=128): 4 K-chunks + 4 V-chunks per thread per tile
    const short* pk[4]; const short* pv[4]; int dk[4], dv[4];
    #pragma unroll
    for(int i=0;i<4;i++){
        int id = i*256 + t;
        int krow = id>>3, kch = id&7;            // 128 rows x 8 chunks
        pk[i] = kh + ((size_t)bh*SKPAD + krow)*64 + (kch ^ (krow&7))*8;
        dk[i] = krow*64 + kch*8;
        int vd = id>>4, vch = id&15;             // 64 d-rows x 16 chunks
        pv[i] = vt + ((size_t)bh*64 + vd)*SKPAD + (vch ^ (vd&7))*8;
        dv[i] = vd*128 + vch*8;
    }
    #define STAGE(kt) { _Pragma("unroll") for(int i_=0;i_<4;i_++){           \
        gload_lds16(pk[i_] + (size_t)(kt)*8192, &lK[(kt)&1][dk[i_]]);        \
        gload_lds16(pv[i_] + (kt)*128,          &lV[(kt)&1][dv[i_]]); } }

    STAGE(0);

    float m_run[2][4], l_run[2][4];
    f32x4 O[2][4] = {};
    #pragma unroll
    for(int qi=0;qi<2;qi++)
        #pragma unroll
        for(int r=0;r<4;r++){ m_run[qi][r] = -3e38f; l_run[qi][r] = 0.f; }

    for(int kt=0; kt<5; kt++){
        if(kt<4){
            STAGE(kt+1);
            asm volatile("s_waitcnt vmcnt(8)" ::: "memory");   // tile kt complete
        } else {
            asm volatile("s_waitcnt vmcnt(0)" ::: "memory");
        }
        __builtin_amdgcn_s_barrier();
        asm volatile("" ::: "memory");

        const short* LK = lK[kt&1]; const short* LV = lV[kt&1];

        #pragma unroll
        for(int qi=0; qi<2; qi++){
            // S = Q K^T: 16 q-rows x 128 keys
            float sv[8][4];
            #pragma unroll
            for(int nt=0; nt<8; nt++){
                int row = nt*16 + c;
                int rx = (row&7)<<3;
                short8 kf0 = *(const short8*)&LK[row*64 + ((g*8) ^ rx)];
                short8 kf1 = *(const short8*)&LK[row*64 + ((32+g*8) ^ rx)];
                __builtin_amdgcn_s_setprio(1);
                f32x4 sa = {};
                sa = __builtin_amdgcn_mfma_f32_16x16x32_bf16(qf[qi][0], kf0, sa, 0,0,0);
                sa = __builtin_amdgcn_mfma_f32_16x16x32_bf16(qf[qi][1], kf1, sa, 0,0,0);
                __builtin_amdgcn_s_setprio(0);
                #pragma unroll
                for(int r=0;r<4;r++) sv[nt][r] = sa[r]*0.18033688011f;  // /8 * log2(e)
            }
            if(kt==4){
                #pragma unroll
                for(int nt=0; nt<8; nt++){
                    int key = 512 + nt*16 + c;
                    if(key >= S_){
                        #pragma unroll
                        for(int r=0;r<4;r++) sv[nt][r] = -3e38f;
                    }
                }
            }
            float fac[4];
            #pragma unroll
            for(int r=0;r<4;r++){
                float mx = sv[0][r];
                #pragma unroll
                for(int nt=1;nt<8;nt++) mx = fmaxf(mx, sv[nt][r]);
                for(int off=1; off<16; off<<=1) mx = fmaxf(mx, __shfl_xor(mx, off));
                float nm = fmaxf(m_run[qi][r], mx);
                fac[r] = __builtin_amdgcn_exp2f(m_run[qi][r] - nm);
                m_run[qi][r] = nm;
            }
            #pragma unroll
            for(int nt=0; nt<8; nt++)
                #pragma unroll
                for(int r=0;r<4;r++){
                    float p = __builtin_amdgcn_exp2f(sv[nt][r] - m_run[qi][r]);
                    int prow = g*4 + r;
                    lP[w*2048 + prow*128 + ((nt*16 + c) ^ ((prow&7)<<3))] = (short)f2bf(p);
                }
            short8 pf[4];
            #pragma unroll
            for(int ks=0; ks<4; ks++)
                pf[ks] = *(const short8*)&lP[w*2048 + c*128 + ((ks*32+g*8) ^ ((c&7)<<3))];
            __builtin_amdgcn_s_setprio(1);
            f32x4 rs = {};
            #pragma unroll
            for(int ks=0; ks<4; ks++)
                rs = __builtin_amdgcn_mfma_f32_16x16x32_bf16(pf[ks], ones, rs, 0,0,0);
            __builtin_amdgcn_s_setprio(0);
            #pragma unroll
            for(int r=0;r<4;r++) l_run[qi][r] = l_run[qi][r]*fac[r] + rs[r];
            #pragma unroll
            for(int nt=0;nt<4;nt++)
                #pragma unroll
                for(int r=0;r<4;r++) O[qi][nt][r] *= fac[r];

            __builtin_amdgcn_s_setprio(1);
            #pragma unroll
            for(int nt=0; nt<4; nt++){
                int vrow = nt*16 + c;
                int rx = (vrow&7)<<3;
                #pragma unroll
                for(int ks=0; ks<4; ks++){
                    short8 vf = *(const short8*)&LV[vrow*128 + ((ks*32+g*8) ^ rx)];
                    O[qi][nt] = __builtin_amdgcn_mfma_f32_16x16x32_bf16(pf[ks], vf, O[qi][nt], 0,0,0);
                }
            }
            __builtin_amdgcn_s_setprio(0);
        }
        asm volatile("s_waitcnt lgkmcnt(0)" ::: "memory");
        __builtin_amdgcn_s_barrier();
        asm volatile("" ::: "memory");
    }
    #undef STAGE

    #pragma unroll
    for(int qi=0; qi<2; qi++)
        #pragma unroll
        for(int nt=0; nt<4; nt++)
            #pragma unroll
            for(int r=0;r<4;r++){
                int s = q0 + w*32 + qi*16 + g*4 + r;
                if(s < S_){
                    float val = O[qi][nt][r] / l_run[qi][r];
                    ctx[((size_t)b*S_ + s)*H_ + h*HD_ + nt*16 + c] = (short)f2bf(val);
                }
            }
}

extern "C" void kernel_launch(void* const* d_in, const int* in_sizes, int n_in,
                              void* d_out, int out_size, void* d_ws, size_t ws_size,
                              hipStream_t stream)
{
    const float* hs = (const float*)d_in[0];
    const float* Wq = (const float*)d_in[1];
    const float* bq = (const float*)d_in[2];
    const float* Wk = (const float*)d_in[3];
    const float* bk = (const float*)d_in[4];
    const float* Wv = (const float*)d_in[5];
    const float* bv = (const float*)d_in[6];
    const float* Wo = (const float*)d_in[7];
    const float* bo = (const float*)d_in[8];
    float* out = (float*)d_out;

    char* ws = (char*)d_ws;
    short* abf = (short*)(ws);
    short* ctx = abf;                               // reuse after QKV GEMM
    short* wqt = (short*)(ws + 7274496);
    short* wkt = (short*)(ws + 7274496 + 1179648);
    short* wvt = (short*)(ws + 7274496 + 2*1179648);
    short* wot = (short*)(ws + 7274496 + 3*1179648);
    short* qh  = (short*)(ws + 11993088);
    short* kh  = (short*)(ws + 19083264);
    short* vt  = (short*)(ws + 26947584);
    // total: 34,811,904 B

    k_prep<<<2733, 256, 0, stream>>>(hs, abf, Wq,Wk,Wv,Wo, wqt,wkt,wvt,wot, kh, vt);
    k_gemm<<<666, 512, 0, stream>>>(abf, wqt, bq,bk,bv, qh,kh,vt, nullptr, 0, 18);
    k_attn<<<dim3(96,5), 256, 0, stream>>>(qh, kh, vt, ctx);
    k_gemm<<<222, 512, 0, stream>>>(ctx, wot, bo,bo,bo, nullptr,nullptr,nullptr, out, 3, 6);
}

// Round 18
// 83.579 us; speedup vs baseline: 1.3689x; 1.0005x over previous
//
#include <hip/hip_runtime.h>
#include <hip/hip_bf16.h>

// out = softmax((X Wq + bq)(X Wk + bk)^T / 8) (X Wv + bv) Wo + bo
// All prune/straight-through ops in the reference are value-wise identity.
//
//   k_prep: fused {hs->bf16 A | W^T bf16 x4 | kh/vt pad zero}   (round-6 proven)
//   k_gemm: 128x128 tile, 512 thr / 8 waves, BK=32, THREE LDS slots (48KB),
//           ONE barrier per K-step, counted vmcnt(2)             (round-17 proven)
//   k_attn: flash attention, QBLK=128/KVBLK=128, 5 key-iters, ONE barrier per
//           iteration: {vmcnt(0); barrier; STAGE(kt+1); compute}. The end
//           barrier is redundant: every ds_read of iter kt-1 is consumed by an
//           MFMA before the wave reaches iter kt's barrier, so the slot that
//           STAGE(kt+1) overwrites is quiescent. 2-slot 80KB LDS unchanged.

#define B_ 8
#define S_ 577
#define H_ 768
#define NH_ 12
#define HD_ 64
#define M_ (B_*S_)     /* 4616 */
#define MPAD 4736
#define BH_ (B_*NH_)   /* 96 */
#define SKPAD 640      /* padded key count */
#define LTS 136        /* padded LDS row stride (shorts) for epilogue tile */

typedef __attribute__((ext_vector_type(8))) short short8;
typedef __attribute__((ext_vector_type(4))) short s16x4;
typedef __attribute__((ext_vector_type(4))) float f32x4;

__device__ inline unsigned short f2bf(float f){
    unsigned int u = __float_as_uint(f);
    u = u + 0x7fffu + ((u>>16)&1u);     // round-to-nearest-even
    return (unsigned short)(u>>16);
}

__device__ inline void gload_lds16(const short* g, short* l){
    __builtin_amdgcn_global_load_lds((const __attribute__((address_space(1))) void*)g,
                                     (__attribute__((address_space(3))) void*)l, 16, 0, 0);
}

// fused prep: blocks [0,1776) cvt | [1776,2352) wt | [2352,2733) pad
__global__ __launch_bounds__(256) void k_prep(
    const float* __restrict__ hs, short* __restrict__ abf,
    const float* __restrict__ Wq, const float* __restrict__ Wk,
    const float* __restrict__ Wv, const float* __restrict__ Wo,
    short* __restrict__ Tq, short* __restrict__ Tk,
    short* __restrict__ Tv, short* __restrict__ To,
    short* __restrict__ kh, short* __restrict__ vt)
{
    const int bid = blockIdx.x, t = threadIdx.x;
    if(bid < 1776){
        int i = bid*256 + t;
        if(bid >= 1731){ *(short8*)(abf + (size_t)i*8) = (short8){}; return; }
        const float4* p = (const float4*)(hs + (size_t)i*8);
        float4 a = p[0], b = p[1];
        short8 v;
        v[0]=(short)f2bf(a.x); v[1]=(short)f2bf(a.y); v[2]=(short)f2bf(a.z); v[3]=(short)f2bf(a.w);
        v[4]=(short)f2bf(b.x); v[5]=(short)f2bf(b.y); v[6]=(short)f2bf(b.z); v[7]=(short)f2bf(b.w);
        *(short8*)(abf + (size_t)i*8) = v;
    } else if(bid < 2352){
        int zidx = bid - 1776;
        int z = zidx & 3, rem = zidx >> 2;
        int kx = rem % 12, ny = rem / 12;
        const float* W = z==0?Wq: z==1?Wk: z==2?Wv:Wo;
        short*       T = z==0?Tq: z==1?Tk: z==2?Tv:To;
        __shared__ float lds[64][65];
        int k0 = kx*64, n0 = ny*64;
        for(int i=0;i<4;i++){
            int row = i*16 + (t>>4);
            int col = (t&15)*4;
            float4 v = *(const float4*)&W[(k0+row)*768 + n0 + col];
            lds[row][col]=v.x; lds[row][col+1]=v.y; lds[row][col+2]=v.z; lds[row][col+3]=v.w;
        }
        __syncthreads();
        for(int i=0;i<4;i++){
            int n = i*16 + (t>>4);
            int k4 = (t&15)*4;
            for(int j=0;j<4;j++)
                T[(n0+n)*768 + k0 + k4 + j] = (short)f2bf(lds[k4+j][n]);
        }
    } else {
        int tid = (bid-2352)*256 + t;
        short8 z = {};
        if(tid < 48384){
            int row_id = tid>>3, ch = tid&7;
            int bh = row_id/63, r = row_id - bh*63;
            *(short8*)&kh[((size_t)bh*SKPAD + 577 + r)*64 + ch*8] = z;
        } else if(tid < 97536){
            int j = tid - 48384;
            int row_id = j>>3, ch = j&7;
            int bh = row_id>>6, d = row_id&63;
            *(short8*)&vt[((size_t)bh*64 + d)*SKPAD + 576 + ch*8] = z;
        }
    }
}

// 128x128 tile GEMM, 512 threads / 8 waves, BK=32, 3-slot single-barrier K-loop.
// mode 0: A[4736][768] @ Tqkv[2304][768]^T -> q/k/v ; mode 3: ctx@Wo+bo -> fp32
__global__ __launch_bounds__(512) void k_gemm(
    const short* __restrict__ A, const short* __restrict__ T,
    const float* __restrict__ b0, const float* __restrict__ b1, const float* __restrict__ b2,
    short* __restrict__ oq, short* __restrict__ ok, short* __restrict__ ovt,
    float* __restrict__ of, int mode, int NT)
{
    __shared__ short sh[24576];            // 48KB: 3 slots x (A 8KB | B 8KB); epi 34816B fits
    const int t = threadIdx.x;

    const int nwg = gridDim.x;
    const int q8 = nwg>>3, r8 = nwg&7;
    const int xcd = blockIdx.x&7, cidx = blockIdx.x>>3;
    const int wg = (xcd<r8 ? xcd*(q8+1) : r8*(q8+1) + (xcd-r8)*q8) + cidx;
    const int mt = wg/NT, ntile = wg - mt*NT;
    const int m0 = mt*128, n0 = ntile*128;

    const int seg = (mode==3)? 0 : n0/768;
    const float* bias = (mode==3)? b0 : (seg==0?b0: seg==1?b1:b2);
    const int nlb = (mode==3)? n0 : n0 - seg*768;

    const int w = t>>6, lane = t&63, g = lane>>4, c = lane&15;
    const int wm = w>>1, wn = w&1;

    // staging (BK=32): thread t covers row t>>2, 16B-chunk t&3; source chunk
    // (t&3) ^ ((row>>1)&3) so LDS[row][ch] = G[row][ch ^ ((row>>1)&3)]
    const int srow = t>>2, sch = t&3;
    const short* gA = A + (size_t)(m0 + srow)*768 + (sch ^ ((srow>>1)&3))*8;
    const short* gB = T + (size_t)(n0 + srow)*768 + (sch ^ ((srow>>1)&3))*8;
    const int dA = srow*32 + sch*8;
    const int dB = 4096 + dA;

    #define SLOT(k) (((k)%3)*8192)
    #define ISS(k) { gload_lds16(gA + (k)*32, &sh[SLOT(k)+dA]); \
                     gload_lds16(gB + (k)*32, &sh[SLOT(k)+dB]); }

    f32x4 acc[2][4] = {};

    // prologue: stage tiles 0,1; counted wait for tile 0
    ISS(0); ISS(1);
    asm volatile("s_waitcnt vmcnt(2)" ::: "memory");
    __builtin_amdgcn_s_barrier();
    asm volatile("" ::: "memory");

    for(int kt=0; kt<24; kt++){
        const short* LA = &sh[SLOT(kt)];
        const short* LB = LA + 4096;
        short8 af[2], bf[4];
        #pragma unroll
        for(int mi=0; mi<2; mi++){
            int row = wm*32 + mi*16 + c;
            af[mi] = *(const short8*)&LA[row*32 + ((g ^ ((row>>1)&3))<<3)];
        }
        #pragma unroll
        for(int ni=0; ni<4; ni++){
            int row = wn*64 + ni*16 + c;
            bf[ni] = *(const short8*)&LB[row*32 + ((g ^ ((row>>1)&3))<<3)];
        }
        if(kt<22) ISS(kt+2);
        asm volatile("s_waitcnt lgkmcnt(0)" ::: "memory");
        __builtin_amdgcn_s_setprio(1);
        #pragma unroll
        for(int mi=0; mi<2; mi++)
            #pragma unroll
            for(int ni=0; ni<4; ni++)
                acc[mi][ni] = __builtin_amdgcn_mfma_f32_16x16x32_bf16(af[mi], bf[ni], acc[mi][ni], 0,0,0);
        __builtin_amdgcn_s_setprio(0);
        if(kt<23){
            if(kt<22){ asm volatile("s_waitcnt vmcnt(2)" ::: "memory"); }
            else     { asm volatile("s_waitcnt vmcnt(0)" ::: "memory"); }
            __builtin_amdgcn_s_barrier();
            asm volatile("" ::: "memory");
        }
    }
    #undef SLOT
    #undef ISS

    if(mode==3){
        #pragma unroll
        for(int mi=0; mi<2; mi++) for(int ni=0; ni<4; ni++){
            #pragma unroll
            for(int r=0; r<4; r++){
                int m = m0 + wm*32 + mi*16 + g*4 + r;   // C/D: row=(lane>>4)*4+reg
                int n = n0 + wn*64 + ni*16 + c;         // C/D: col=lane&15
                if(m >= M_) continue;
                of[(size_t)m*768 + n] = acc[mi][ni][r] + bias[n];
            }
        }
        return;
    }

    __syncthreads();   // all reads of sh done before epilogue overwrite

    if(seg==2){
        #pragma unroll
        for(int mi=0;mi<2;mi++)
            #pragma unroll
            for(int ni=0;ni<4;ni++){
                int nl_ = wn*64 + ni*16 + c;
                float bv = bias[nlb + nl_];
                s16x4 pk;
                #pragma unroll
                for(int r=0;r<4;r++) pk[r] = (short)f2bf(acc[mi][ni][r] + bv);
                int ml0 = wm*32 + mi*16 + g*4;
                *(s16x4*)&sh[nl_*LTS + ml0] = pk;       // transposed: [n][m]
            }
    } else {
        #pragma unroll
        for(int mi=0;mi<2;mi++)
            #pragma unroll
            for(int ni=0;ni<4;ni++){
                int nl_ = wn*64 + ni*16 + c;
                float bv = bias[nlb + nl_];
                #pragma unroll
                for(int r=0;r<4;r++){
                    int ml = wm*32 + mi*16 + g*4 + r;
                    sh[ml*LTS + nl_] = (short)f2bf(acc[mi][ni][r] + bv);
                }
            }
    }
    __syncthreads();

    #pragma unroll
    for(int i=0;i<4;i++){
        int idx = i*512 + t;
        int rp = idx>>4, ch = idx&15;
        short8 v8 = *(const short8*)&sh[rp*LTS + ch*8];
        if(seg==2){
            int nl = nlb + rp, hh = nl>>6, dd = nl&63;
            int mg = m0 + ch*8;
            if(mg < M_){
                int b0_ = mg/S_, s0 = mg - b0_*S_;
                if(s0+7 < S_ && mg+7 < M_){
                    *(short8*)&ovt[(((size_t)b0_*NH_+hh)*HD_+dd)*SKPAD + s0] = v8;
                } else {
                    for(int j=0;j<8;j++){
                        int m=mg+j;
                        if(m<M_){ int bj=m/S_, sj=m-bj*S_;
                            ovt[(((size_t)bj*NH_+hh)*HD_+dd)*SKPAD+sj]=v8[j]; }
                    }
                }
            }
        } else {
            int m = m0 + rp;
            if(m < M_){
                int b0_ = m/S_, s0 = m - b0_*S_;
                int nl = nlb + ch*8, hh = nl>>6, dd = nl&63;
                if(seg==1) *(short8*)&ok[(((size_t)b0_*NH_+hh)*SKPAD + s0)*HD_ + dd] = v8;
                else       *(short8*)&oq[(((size_t)b0_*NH_+hh)*S_   + s0)*HD_ + dd] = v8;
            }
        }
    }
}

// flash attention: QBLK=128, KVBLK=128, 5 key-iterations, ONE barrier per
// iteration ({vmcnt(0); barrier; STAGE(kt+1); compute} - end barrier proven
// redundant via MFMA data-dependence). 2-slot dbuf, per-qi softmax, exp2,
// MFMA row-sum, setprio.
__global__ __launch_bounds__(256) void k_attn(
    const short* __restrict__ qh, const short* __restrict__ kh, const short* __restrict__ vt,
    short* __restrict__ ctx)
{
    __shared__ short lK[2][128*64], lV[2][64*128], lP[4*2048];
    const int t = threadIdx.x;
    const int w = t>>6, lane = t&63, g = lane>>4, c = lane&15;
    const int bh = blockIdx.x, b = bh/NH_, h = bh%NH_;
    const int q0 = blockIdx.y*128;

    // per-wave Q staging (32 rows) into own lP region, then frags to regs
    #pragma unroll
    for(int i=0;i<4;i++){
        int row = i*8 + (lane>>3);
        int e8 = (lane&7)*8;
        int s = q0 + w*32 + row;
        short8 v = {};
        if(s < S_) v = *(const short8*)&qh[((size_t)bh*S_ + s)*HD_ + e8];
        *(short8*)&lP[w*2048 + row*64 + (e8 ^ ((row&7)<<3))] = v;
    }
    short8 qf[2][2];
    #pragma unroll
    for(int qi=0; qi<2; qi++)
        #pragma unroll
        for(int ks=0; ks<2; ks++)
            qf[qi][ks] = *(const short8*)&lP[w*2048 + (qi*16+c)*64 + ((ks*32+g*8) ^ ((c&7)<<3))];

    short8 ones;
    #pragma unroll
    for(int j=0;j<8;j++) ones[j] = (short)0x3F80;    // bf16 1.0

    // staging maps (KVBLK=128): 4 K-chunks + 4 V-chunks per thread per tile
    const short* pk[4]; const short* pv[4]; int dk[4], dv[4];
    #pragma unroll
    for(int i=0;i<4;i++){
        int id = i*256 + t;
        int krow = id>>3, kch = id&7;            // 128 rows x 8 chunks
        pk[i] = kh + ((size_t)bh*SKPAD + krow)*64 + (kch ^ (krow&7))*8;
        dk[i] = krow*64 + kch*8;
        int vd = id>>4, vch = id&15;             // 64 d-rows x 16 chunks
        pv[i] = vt + ((size_t)bh*64 + vd)*SKPAD + (vch ^ (vd&7))*8;
        dv[i] = vd*128 + vch*8;
    }
    #define STAGE(kt) { _Pragma("unroll") for(int i_=0;i_<4;i_++){           \
        gload_lds16(pk[i_] + (size_t)(kt)*8192, &lK[(kt)&1][dk[i_]]);        \
        gload_lds16(pv[i_] + (kt)*128,          &lV[(kt)&1][dv[i_]]); } }

    STAGE(0);

    float m_run[2][4], l_run[2][4];
    f32x4 O[2][4] = {};
    #pragma unroll
    for(int qi=0;qi<2;qi++)
        #pragma unroll
        for(int r=0;r<4;r++){ m_run[qi][r] = -3e38f; l_run[qi][r] = 0.f; }

    for(int kt=0; kt<5; kt++){
        // own tile-kt loads complete; barrier => all waves' loads complete AND
        // all waves' iter kt-1 ds_reads consumed (MFMA data-dependence)
        asm volatile("s_waitcnt vmcnt(0)" ::: "memory");
        __builtin_amdgcn_s_barrier();
        asm volatile("" ::: "memory");
        if(kt<4) STAGE(kt+1);    // overwrites slot (kt+1)&1: quiescent per above

        const short* LK = lK[kt&1]; const short* LV = lV[kt&1];

        #pragma unroll
        for(int qi=0; qi<2; qi++){
            // S = Q K^T: 16 q-rows x 128 keys
            float sv[8][4];
            #pragma unroll
            for(int nt=0; nt<8; nt++){
                int row = nt*16 + c;
                int rx = (row&7)<<3;
                short8 kf0 = *(const short8*)&LK[row*64 + ((g*8) ^ rx)];
                short8 kf1 = *(const short8*)&LK[row*64 + ((32+g*8) ^ rx)];
                __builtin_amdgcn_s_setprio(1);
                f32x4 sa = {};
                sa = __builtin_amdgcn_mfma_f32_16x16x32_bf16(qf[qi][0], kf0, sa, 0,0,0);
                sa = __builtin_amdgcn_mfma_f32_16x16x32_bf16(qf[qi][1], kf1, sa, 0,0,0);
                __builtin_amdgcn_s_setprio(0);
                #pragma unroll
                for(int r=0;r<4;r++) sv[nt][r] = sa[r]*0.18033688011f;  // /8 * log2(e)
            }
            if(kt==4){
                #pragma unroll
                for(int nt=0; nt<8; nt++){
                    int key = 512 + nt*16 + c;
                    if(key >= S_){
                        #pragma unroll
                        for(int r=0;r<4;r++) sv[nt][r] = -3e38f;
                    }
                }
            }
            float fac[4];
            #pragma unroll
            for(int r=0;r<4;r++){
                float mx = sv[0][r];
                #pragma unroll
                for(int nt=1;nt<8;nt++) mx = fmaxf(mx, sv[nt][r]);
                for(int off=1; off<16; off<<=1) mx = fmaxf(mx, __shfl_xor(mx, off));
                float nm = fmaxf(m_run[qi][r], mx);
                fac[r] = __builtin_amdgcn_exp2f(m_run[qi][r] - nm);
                m_run[qi][r] = nm;
            }
            #pragma unroll
            for(int nt=0; nt<8; nt++)
                #pragma unroll
                for(int r=0;r<4;r++){
                    float p = __builtin_amdgcn_exp2f(sv[nt][r] - m_run[qi][r]);
                    int prow = g*4 + r;
                    lP[w*2048 + prow*128 + ((nt*16 + c) ^ ((prow&7)<<3))] = (short)f2bf(p);
                }
            short8 pf[4];
            #pragma unroll
            for(int ks=0; ks<4; ks++)
                pf[ks] = *(const short8*)&lP[w*2048 + c*128 + ((ks*32+g*8) ^ ((c&7)<<3))];
            __builtin_amdgcn_s_setprio(1);
            f32x4 rs = {};
            #pragma unroll
            for(int ks=0; ks<4; ks++)
                rs = __builtin_amdgcn_mfma_f32_16x16x32_bf16(pf[ks], ones, rs, 0,0,0);
            __builtin_amdgcn_s_setprio(0);
            #pragma unroll
            for(int r=0;r<4;r++) l_run[qi][r] = l_run[qi][r]*fac[r] + rs[r];
            #pragma unroll
            for(int nt=0;nt<4;nt++)
                #pragma unroll
                for(int r=0;r<4;r++) O[qi][nt][r] *= fac[r];

            __builtin_amdgcn_s_setprio(1);
            #pragma unroll
            for(int nt=0; nt<4; nt++){
                int vrow = nt*16 + c;
                int rx = (vrow&7)<<3;
                #pragma unroll
                for(int ks=0; ks<4; ks++){
                    short8 vf = *(const short8*)&LV[vrow*128 + ((ks*32+g*8) ^ rx)];
                    O[qi][nt] = __builtin_amdgcn_mfma_f32_16x16x32_bf16(pf[ks], vf, O[qi][nt], 0,0,0);
                }
            }
            __builtin_amdgcn_s_setprio(0);
        }
    }
    #undef STAGE

    #pragma unroll
    for(int qi=0; qi<2; qi++)
        #pragma unroll
        for(int nt=0; nt<4; nt++)
            #pragma unroll
            for(int r=0;r<4;r++){
                int s = q0 + w*32 + qi*16 + g*4 + r;
                if(s < S_){
                    float val = O[qi][nt][r] / l_run[qi][r];
                    ctx[((size_t)b*S_ + s)*H_ + h*HD_ + nt*16 + c] = (short)f2bf(val);
                }
            }
}

extern "C" void kernel_launch(void* const* d_in, const int* in_sizes, int n_in,
                              void* d_out, int out_size, void* d_ws, size_t ws_size,
                              hipStream_t stream)
{
    const float* hs = (const float*)d_in[0];
    const float* Wq = (const float*)d_in[1];
    const float* bq = (const float*)d_in[2];
    const float* Wk = (const float*)d_in[3];
    const float* bk = (const float*)d_in[4];
    const float* Wv = (const float*)d_in[5];
    const float* bv = (const float*)d_in[6];
    const float* Wo = (const float*)d_in[7];
    const float* bo = (const float*)d_in[8];
    float* out = (float*)d_out;

    char* ws = (char*)d_ws;
    short* abf = (short*)(ws);
    short* ctx = abf;                               // reuse after QKV GEMM
    short* wqt = (short*)(ws + 7274496);
    short* wkt = (short*)(ws + 7274496 + 1179648);
    short* wvt = (short*)(ws + 7274496 + 2*1179648);
    short* wot = (short*)(ws + 7274496 + 3*1179648);
    short* qh  = (short*)(ws + 11993088);
    short* kh  = (short*)(ws + 19083264);
    short* vt  = (short*)(ws + 26947584);
    // total: 34,811,904 B

    k_prep<<<2733, 256, 0, stream>>>(hs, abf, Wq,Wk,Wv,Wo, wqt,wkt,wvt,wot, kh, vt);
    k_gemm<<<666, 512, 0, stream>>>(abf, wqt, bq,bk,bv, qh,kh,vt, nullptr, 0, 18);
    k_attn<<<dim3(96,5), 256, 0, stream>>>(qh, kh, vt, ctx);
    k_gemm<<<222, 512, 0, stream>>>(ctx, wot, bo,bo,bo, nullptr,nullptr,nullptr, out, 3, 6);
}